// Round 1
// baseline (481.605 us; speedup 1.0000x reference)
//
#include <hip/hip_runtime.h>
#include <math.h>

#define TPB 256

static __device__ __forceinline__ void atomAddD(double* p, double v) {
  __hip_atomic_fetch_add(p, v, __ATOMIC_RELAXED, __HIP_MEMORY_SCOPE_AGENT);
}

static __device__ __forceinline__ double bredsum(double v) {
  __shared__ double sb[TPB];
  int t = threadIdx.x;
  sb[t] = v;
  __syncthreads();
  for (int o = TPB / 2; o > 0; o >>= 1) {
    if (t < o) sb[t] += sb[t + o];
    __syncthreads();
  }
  double r = sb[0];
  __syncthreads();
  return r;
}

// cot weights per corner, matching _cot_edges (Heron area with 1e-12 clip)
static __device__ __forceinline__ void faceCots(const double* p0, const double* p1,
                                                const double* p2, double* cot) {
  double A2 = 0, B2 = 0, C2 = 0;
  for (int c = 0; c < 3; c++) {
    double d12 = p1[c] - p2[c]; A2 += d12 * d12;
    double d02 = p0[c] - p2[c]; B2 += d02 * d02;
    double d01 = p0[c] - p1[c]; C2 += d01 * d01;
  }
  double A = sqrt(A2), Bl = sqrt(B2), C = sqrt(C2);
  double s = 0.5 * (A + Bl + C);
  double pr = s * (s - A) * (s - Bl) * (s - C);
  pr = pr < 1e-12 ? 1e-12 : pr;
  double inv4 = 1.0 / (4.0 * sqrt(pr));
  cot[0] = (B2 + C2 - A2) * inv4;
  cot[1] = (A2 + C2 - B2) * inv4;
  cot[2] = (A2 + B2 - C2) * inv4;
}

__global__ void kInitRowmin(unsigned* rm, int n) {
  int i = blockIdx.x * blockDim.x + threadIdx.x;
  if (i < n) rm[i] = 0x7f800000u;  // +inf
}

__global__ void kFaceAreas(const float* verts, const int* faces, double* areas,
                           int B, int Vn, int F) {
  int i = blockIdx.x * blockDim.x + threadIdx.x;
  if (i >= B * F) return;
  int b = i / F, f = i % F;
  const float* vb = verts + (size_t)b * Vn * 3;
  int i0 = faces[f * 3], i1 = faces[f * 3 + 1], i2 = faces[f * 3 + 2];
  double ax = (double)vb[i1 * 3 + 0] - vb[i0 * 3 + 0];
  double ay = (double)vb[i1 * 3 + 1] - vb[i0 * 3 + 1];
  double az = (double)vb[i1 * 3 + 2] - vb[i0 * 3 + 2];
  double bx = (double)vb[i2 * 3 + 0] - vb[i0 * 3 + 0];
  double by = (double)vb[i2 * 3 + 1] - vb[i0 * 3 + 1];
  double bz = (double)vb[i2 * 3 + 2] - vb[i0 * 3 + 2];
  double cx = ay * bz - az * by;
  double cy = az * bx - ax * bz;
  double cz = ax * by - ay * bx;
  areas[i] = 0.5 * sqrt(cx * cx + cy * cy + cz * cz);
}

// two-level inclusive scan over F doubles per batch (chunk = 1024)
__global__ void kScan1(double* a, double* bsum, int F, int nc) {
  int blk = blockIdx.x;
  int b = blk / nc, c = blk % nc;
  int t = threadIdx.x;
  int f = c * 1024 + t;
  __shared__ double s[1024];
  double v = (f < F) ? a[(size_t)b * F + f] : 0.0;
  s[t] = v;
  __syncthreads();
  for (int o = 1; o < 1024; o <<= 1) {
    double ad = (t >= o) ? s[t - o] : 0.0;
    __syncthreads();
    s[t] += ad;
    __syncthreads();
  }
  if (f < F) a[(size_t)b * F + f] = s[t];
  if (t == 1023) bsum[(size_t)b * nc + c] = s[1023];
}

__global__ void kScan2(const double* bsum, double* boffs, int nc) {
  int b = blockIdx.x, t = threadIdx.x;
  __shared__ double s[1024];
  double v = (t < nc) ? bsum[(size_t)b * nc + t] : 0.0;
  s[t] = v;
  __syncthreads();
  for (int o = 1; o < 1024; o <<= 1) {
    double ad = (t >= o) ? s[t - o] : 0.0;
    __syncthreads();
    s[t] += ad;
    __syncthreads();
  }
  if (t < nc) boffs[(size_t)b * nc + t] = s[t] - v;  // exclusive
}

__global__ void kScan3(double* a, const double* boffs, int F, int nc) {
  int blk = blockIdx.x;
  int b = blk / nc, c = blk % nc;
  int f = c * 1024 + threadIdx.x;
  if (f < F) a[(size_t)b * F + f] += boffs[(size_t)b * nc + c];
}

__global__ void kSample(const float* verts, const int* faces, const double* cdf,
                        const float* rfu, const float* rbary, float* samples,
                        int B, int Vn, int F, int S) {
  int i = blockIdx.x * blockDim.x + threadIdx.x;
  if (i >= B * S) return;
  int b = i / S;
  const double* c = cdf + (size_t)b * F;
  double total = c[F - 1];
  double tgt = (double)rfu[i] * total;
  int lo = 0, hi = F;  // lower_bound: first idx with cdf[idx] >= tgt
  while (lo < hi) {
    int m = (lo + hi) >> 1;
    if (c[m] < tgt) lo = m + 1; else hi = m;
  }
  int f = lo < F ? lo : F - 1;
  const float* vb = verts + (size_t)b * Vn * 3;
  int i0 = faces[f * 3], i1 = faces[f * 3 + 1], i2 = faces[f * 3 + 2];
  float r0 = rbary[(size_t)i * 2], r1 = rbary[(size_t)i * 2 + 1];
  float su = sqrtf(r0);
  float w0 = 1.f - su, w1 = su * (1.f - r1), w2 = su * r1;
  samples[(size_t)i * 3 + 0] = w0 * vb[i0 * 3 + 0] + w1 * vb[i1 * 3 + 0] + w2 * vb[i2 * 3 + 0];
  samples[(size_t)i * 3 + 1] = w0 * vb[i0 * 3 + 1] + w1 * vb[i1 * 3 + 1] + w2 * vb[i2 * 3 + 1];
  samples[(size_t)i * 3 + 2] = w0 * vb[i0 * 3 + 2] + w1 * vb[i1 * 3 + 2] + w2 * vb[i2 * 3 + 2];
}

// row-mins of the SxS pairwise sq-dist matrix; grid (row-tiles, j-splits, B)
__global__ void kChamfer(const float* X, const float* Y, unsigned* rowmin, int S) {
  int b = blockIdx.z;
  int i = blockIdx.x * TPB + threadIdx.x;
  int jl = (S + gridDim.y - 1) / gridDim.y;
  int j0 = blockIdx.y * jl;
  int j1 = min(S, j0 + jl);
  const float* Xb = X + (size_t)b * S * 3;
  const float* Yb = Y + (size_t)b * S * 3;
  float x0 = 0, x1 = 0, x2 = 0;
  bool act = (i < S);
  if (act) { x0 = Xb[i * 3]; x1 = Xb[i * 3 + 1]; x2 = Xb[i * 3 + 2]; }
  float mn = __int_as_float(0x7f800000);
  __shared__ float sy[TPB * 3];
  for (int jt = j0; jt < j1; jt += TPB) {
    int n = min(TPB, j1 - jt);
    if ((int)threadIdx.x < n) {
      sy[threadIdx.x * 3 + 0] = Yb[(size_t)(jt + threadIdx.x) * 3 + 0];
      sy[threadIdx.x * 3 + 1] = Yb[(size_t)(jt + threadIdx.x) * 3 + 1];
      sy[threadIdx.x * 3 + 2] = Yb[(size_t)(jt + threadIdx.x) * 3 + 2];
    }
    __syncthreads();
    if (act) {
      for (int k = 0; k < n; k++) {
        float dx = x0 - sy[k * 3], dy = x1 - sy[k * 3 + 1], dz = x2 - sy[k * 3 + 2];
        float d = dx * dx + dy * dy + dz * dz;
        mn = fminf(mn, d);
      }
    }
    __syncthreads();
  }
  if (act) atomicMin(&rowmin[(size_t)b * S + i], __float_as_uint(mn));
}

__global__ void kReduceRowmin(const unsigned* rm, int n, double* acc) {
  int i = blockIdx.x * TPB + threadIdx.x;
  double v = 0.0;
  if (i < n) v = (double)__uint_as_float(rm[i]);
  double r = bredsum(v);
  if (threadIdx.x == 0) atomAddD(acc, r);
}

__global__ void kEdgeStd(const float* vstd, const int* edges, int E, double* acc) {
  int i = blockIdx.x * TPB + threadIdx.x;
  double val = 0.0;
  if (i < E) {
    int e0 = edges[(size_t)i * 2], e1 = edges[(size_t)i * 2 + 1];
    double dx = (double)vstd[e0 * 3 + 0] - vstd[e1 * 3 + 0];
    double dy = (double)vstd[e0 * 3 + 1] - vstd[e1 * 3 + 1];
    double dz = (double)vstd[e0 * 3 + 2] - vstd[e1 * 3 + 2];
    val = sqrt(dx * dx + dy * dy + dz * dz);
  }
  double r = bredsum(val);
  if (threadIdx.x == 0) atomAddD(acc, r);
}

__global__ void kEdgeLoss(const float* vscr, const int* edges, int B, int Vn, int E,
                          const double* tacc, double* acc) {
  int i = blockIdx.x * TPB + threadIdx.x;
  double tl = tacc[0] / (double)E;
  double val = 0.0;
  if (i < B * E) {
    int b = i / E, e = i % E;
    const float* vb = vscr + (size_t)b * Vn * 3;
    int e0 = edges[(size_t)e * 2], e1 = edges[(size_t)e * 2 + 1];
    double dx = (double)vb[e0 * 3 + 0] - vb[e1 * 3 + 0];
    double dy = (double)vb[e0 * 3 + 1] - vb[e1 * 3 + 1];
    double dz = (double)vb[e0 * 3 + 2] - vb[e1 * 3 + 2];
    double l = sqrt(dx * dx + dy * dy + dz * dz);
    double d = l - tl;
    val = d * d;
  }
  double r = bredsum(val);
  if (threadIdx.x == 0) atomAddD(acc, r);
}

__global__ void kLapScatter(const float* verts, const int* faces, double* Lv, double* rw,
                            int B, int Vn, int F) {
  int i = blockIdx.x * TPB + threadIdx.x;
  if (i >= B * F) return;
  int b = i / F, f = i % F;
  const float* vb = verts + (size_t)b * Vn * 3;
  int i0 = faces[f * 3], i1 = faces[f * 3 + 1], i2 = faces[f * 3 + 2];
  double p0[3], p1[3], p2[3];
  for (int c = 0; c < 3; c++) {
    p0[c] = vb[i0 * 3 + c]; p1[c] = vb[i1 * 3 + c]; p2[c] = vb[i2 * 3 + c];
  }
  double cot[3];
  faceCots(p0, p1, p2, cot);
  double* Lvb = Lv + (size_t)b * Vn * 3;
  double* rwb = rw + (size_t)b * Vn;
  for (int c = 0; c < 3; c++) {
    atomAddD(&Lvb[(size_t)i0 * 3 + c], cot[1] * p2[c] + cot[2] * p1[c]);
    atomAddD(&Lvb[(size_t)i1 * 3 + c], cot[0] * p2[c] + cot[2] * p0[c]);
    atomAddD(&Lvb[(size_t)i2 * 3 + c], cot[1] * p0[c] + cot[0] * p1[c]);
  }
  atomAddD(&rwb[i0], cot[1] + cot[2]);
  atomAddD(&rwb[i1], cot[0] + cot[2]);
  atomAddD(&rwb[i2], cot[0] + cot[1]);
}

__global__ void kLapNorm(const float* verts, const double* Lv, const double* rw,
                         int B, int Vn, double* acc) {
  int i = blockIdx.x * TPB + threadIdx.x;
  double val = 0.0;
  if (i < B * Vn) {
    double r = rw[i];
    double inv = (r > 0.0) ? 1.0 / fmax(r, 1e-12) : 0.0;
    const float* vp = verts + (size_t)i * 3;
    double dx = Lv[(size_t)i * 3 + 0] * inv - (double)vp[0];
    double dy = Lv[(size_t)i * 3 + 1] * inv - (double)vp[1];
    double dz = Lv[(size_t)i * 3 + 2] * inv - (double)vp[2];
    val = sqrt(dx * dx + dy * dy + dz * dz);
  }
  double r = bredsum(val);
  if (threadIdx.x == 0) atomAddD(acc, r);
}

__global__ void kRigidScatter(const float* vstd, const float* vscr, const int* faces,
                              double* Smat, int B, int Vn, int F) {
  int i = blockIdx.x * TPB + threadIdx.x;
  if (i >= B * F) return;
  int b = i / F, f = i % F;
  int i0 = faces[f * 3], i1 = faces[f * 3 + 1], i2 = faces[f * 3 + 2];
  const float* cb = vscr + (size_t)b * Vn * 3;
  double p0[3], p1[3], p2[3], q0[3], q1[3], q2[3];
  for (int c = 0; c < 3; c++) {
    p0[c] = vstd[i0 * 3 + c]; p1[c] = vstd[i1 * 3 + c]; p2[c] = vstd[i2 * 3 + c];
    q0[c] = cb[i0 * 3 + c];   q1[c] = cb[i1 * 3 + c];   q2[c] = cb[i2 * 3 + c];
  }
  double cot[3];
  faceCots(p0, p1, p2, cot);
  double e01s[3], e02s[3], e12s[3], e01c[3], e02c[3], e12c[3];
  for (int c = 0; c < 3; c++) {
    e01s[c] = p0[c] - p1[c]; e02s[c] = p0[c] - p2[c]; e12s[c] = p1[c] - p2[c];
    e01c[c] = q0[c] - q1[c]; e02c[c] = q0[c] - q2[c]; e12c[c] = q1[c] - q2[c];
  }
  double* S0 = Smat + ((size_t)b * Vn + i0) * 9;
  double* S1 = Smat + ((size_t)b * Vn + i1) * 9;
  double* S2 = Smat + ((size_t)b * Vn + i2) * 9;
  for (int r = 0; r < 3; r++)
    for (int c = 0; c < 3; c++) {
      double t01 = cot[2] * e01s[r] * e01c[c];
      double t02 = cot[1] * e02s[r] * e02c[c];
      double t12 = cot[0] * e12s[r] * e12c[c];
      atomAddD(&S0[r * 3 + c], t01 + t02);
      atomAddD(&S1[r * 3 + c], t01 + t12);
      atomAddD(&S2[r * 3 + c], t02 + t12);
    }
}

// Kabsch rotation via Jacobi eigen of S^T S; det-flip handled by
// R = v1 u1^T + v2 u2^T + (v1 x v2)(u1 x u2)^T
__global__ void kRigidR(const double* Smat, double* Rmat, int n) {
  int i = blockIdx.x * TPB + threadIdx.x;
  if (i >= n) return;
  const double* sp = Smat + (size_t)i * 9;
  double S[3][3];
  for (int r = 0; r < 3; r++)
    for (int c = 0; c < 3; c++) S[r][c] = sp[r * 3 + c];
  double A[3][3];
  for (int a = 0; a < 3; a++)
    for (int c = 0; c < 3; c++) {
      double t = 0;
      for (int r = 0; r < 3; r++) t += S[r][a] * S[r][c];
      A[a][c] = t;
    }
  double V[3][3] = {{1, 0, 0}, {0, 1, 0}, {0, 0, 1}};
  const int PP[3] = {0, 0, 1}, QQ[3] = {1, 2, 2};
  for (int sw = 0; sw < 12; sw++) {
    double off = fabs(A[0][1]) + fabs(A[0][2]) + fabs(A[1][2]);
    double dia = fabs(A[0][0]) + fabs(A[1][1]) + fabs(A[2][2]);
    if (!(off > dia * 1e-15)) break;
    for (int pi = 0; pi < 3; pi++) {
      int p = PP[pi], q = QQ[pi];
      double apq = A[p][q];
      if (apq == 0.0) continue;
      double app = A[p][p], aqq = A[q][q];
      double theta = (aqq - app) / (2.0 * apq);
      double t = 1.0 / (fabs(theta) + sqrt(theta * theta + 1.0));
      if (theta < 0.0) t = -t;
      double c = 1.0 / sqrt(t * t + 1.0), sn = t * c;
      A[p][p] = app - t * apq;
      A[q][q] = aqq + t * apq;
      A[p][q] = A[q][p] = 0.0;
      int r = 3 - p - q;
      double arp = A[r][p], arq = A[r][q];
      A[r][p] = A[p][r] = c * arp - sn * arq;
      A[r][q] = A[q][r] = sn * arp + c * arq;
      for (int k = 0; k < 3; k++) {
        double vkp = V[k][p], vkq = V[k][q];
        V[k][p] = c * vkp - sn * vkq;
        V[k][q] = sn * vkp + c * vkq;
      }
    }
  }
  double lam[3] = {A[0][0], A[1][1], A[2][2]};
  int o0 = 0, o1 = 1, o2 = 2;
  if (lam[o0] < lam[o1]) { int t = o0; o0 = o1; o1 = t; }
  if (lam[o0] < lam[o2]) { int t = o0; o0 = o2; o2 = t; }
  if (lam[o1] < lam[o2]) { int t = o1; o1 = o2; o2 = t; }
  double v1[3] = {V[0][o0], V[1][o0], V[2][o0]};
  double v2[3] = {V[0][o1], V[1][o1], V[2][o1]};
  double R[3][3] = {{1, 0, 0}, {0, 1, 0}, {0, 0, 1}};
  double b1[3], b2[3];
  for (int r = 0; r < 3; r++) {
    b1[r] = S[r][0] * v1[0] + S[r][1] * v1[1] + S[r][2] * v1[2];
    b2[r] = S[r][0] * v2[0] + S[r][1] * v2[1] + S[r][2] * v2[2];
  }
  double n1 = sqrt(b1[0] * b1[0] + b1[1] * b1[1] + b1[2] * b1[2]);
  if (n1 > 1e-300 && isfinite(n1)) {
    double u1[3] = {b1[0] / n1, b1[1] / n1, b1[2] / n1};
    double dp = u1[0] * b2[0] + u1[1] * b2[1] + u1[2] * b2[2];
    for (int r = 0; r < 3; r++) b2[r] -= dp * u1[r];
    double n2 = sqrt(b2[0] * b2[0] + b2[1] * b2[1] + b2[2] * b2[2]);
    double u2[3];
    if (n2 > n1 * 1e-14) {
      u2[0] = b2[0] / n2; u2[1] = b2[1] / n2; u2[2] = b2[2] / n2;
    } else {
      int k = 0;
      if (fabs(u1[1]) < fabs(u1[k])) k = 1;
      if (fabs(u1[2]) < fabs(u1[k])) k = 2;
      double e0 = (k == 0) - u1[k] * u1[0];
      double e1 = (k == 1) - u1[k] * u1[1];
      double e2 = (k == 2) - u1[k] * u1[2];
      double nw = sqrt(e0 * e0 + e1 * e1 + e2 * e2);
      u2[0] = e0 / nw; u2[1] = e1 / nw; u2[2] = e2 / nw;
    }
    double u3[3] = {u1[1] * u2[2] - u1[2] * u2[1],
                    u1[2] * u2[0] - u1[0] * u2[2],
                    u1[0] * u2[1] - u1[1] * u2[0]};
    double w3[3] = {v1[1] * v2[2] - v1[2] * v2[1],
                    v1[2] * v2[0] - v1[0] * v2[2],
                    v1[0] * v2[1] - v1[1] * v2[0]};
    for (int r = 0; r < 3; r++)
      for (int c = 0; c < 3; c++)
        R[r][c] = v1[r] * u1[c] + v2[r] * u2[c] + w3[r] * u3[c];
  }
  double* rp = Rmat + (size_t)i * 9;
  for (int r = 0; r < 3; r++)
    for (int c = 0; c < 3; c++) rp[r * 3 + c] = R[r][c];
}

static __device__ __forceinline__ double resid(const double* R, const double* es,
                                               const double* ec) {
  double r0 = ec[0] - (R[0] * es[0] + R[1] * es[1] + R[2] * es[2]);
  double r1 = ec[1] - (R[3] * es[0] + R[4] * es[1] + R[5] * es[2]);
  double r2 = ec[2] - (R[6] * es[0] + R[7] * es[1] + R[8] * es[2]);
  return r0 * r0 + r1 * r1 + r2 * r2;
}

__global__ void kRigidRes(const float* vstd, const float* vscr, const int* faces,
                          const double* Rmat, int B, int Vn, int F, double* acc) {
  int i = blockIdx.x * TPB + threadIdx.x;
  double val = 0.0;
  if (i < B * F) {
    int b = i / F, f = i % F;
    int i0 = faces[f * 3], i1 = faces[f * 3 + 1], i2 = faces[f * 3 + 2];
    const float* cb = vscr + (size_t)b * Vn * 3;
    double p0[3], p1[3], p2[3], q0[3], q1[3], q2[3];
    for (int c = 0; c < 3; c++) {
      p0[c] = vstd[i0 * 3 + c]; p1[c] = vstd[i1 * 3 + c]; p2[c] = vstd[i2 * 3 + c];
      q0[c] = cb[i0 * 3 + c];   q1[c] = cb[i1 * 3 + c];   q2[c] = cb[i2 * 3 + c];
    }
    double cot[3];
    faceCots(p0, p1, p2, cot);
    double e01s[3], e02s[3], e12s[3], e01c[3], e02c[3], e12c[3];
    for (int c = 0; c < 3; c++) {
      e01s[c] = p0[c] - p1[c]; e02s[c] = p0[c] - p2[c]; e12s[c] = p1[c] - p2[c];
      e01c[c] = q0[c] - q1[c]; e02c[c] = q0[c] - q2[c]; e12c[c] = q1[c] - q2[c];
    }
    const double* R0 = Rmat + ((size_t)b * Vn + i0) * 9;
    const double* R1 = Rmat + ((size_t)b * Vn + i1) * 9;
    const double* R2 = Rmat + ((size_t)b * Vn + i2) * 9;
    val = cot[1] * resid(R0, e02s, e02c) + cot[2] * resid(R0, e01s, e01c)
        + cot[0] * resid(R1, e12s, e12c) + cot[2] * resid(R1, e01s, e01c)
        + cot[1] * resid(R2, e02s, e02c) + cot[0] * resid(R2, e12s, e12c);
  }
  double r = bredsum(val);
  if (threadIdx.x == 0) atomAddD(acc, r);
}

__global__ void kFinalize(const double* acc, float* out, int B, int Vn, int S, int E) {
  if (blockIdx.x == 0 && threadIdx.x == 0) {
    out[0] = (float)(acc[0] / ((double)B * S));   // loss_p0 (both directions summed)
    out[1] = 1e-5f;                               // loss_n1
    out[2] = (float)(acc[1] / ((double)B * Vn));  // loss_lap
    out[3] = (float)(acc[3] / ((double)B * E));   // loss_edge
    out[4] = (float)(acc[4] / ((double)B * Vn));  // loss_rigid
  }
}

extern "C" void kernel_launch(void* const* d_in, const int* in_sizes, int n_in,
                              void* d_out, int out_size, void* d_ws, size_t ws_size,
                              hipStream_t stream) {
  const float* vscr = (const float*)d_in[0];
  const float* vstd = (const float*)d_in[1];
  const float* trg  = (const float*)d_in[2];
  const float* rfu  = (const float*)d_in[3];
  const float* rby  = (const float*)d_in[4];
  const int* faces  = (const int*)d_in[5];
  const int* edges  = (const int*)d_in[6];
  float* out = (float*)d_out;

  int nVs = in_sizes[1];
  int Vn = nVs / 3;
  int B = in_sizes[0] / nVs;
  int S = in_sizes[3] / B;
  int F = in_sizes[5] / 3;
  int E = in_sizes[6] / 2;
  int nc = (F + 1023) / 1024;

  char* p = (char*)d_ws;
  auto alloc = [&](size_t bytes) -> void* {
    void* r = (void*)p;
    p += (bytes + 255) & ~(size_t)255;
    return r;
  };
  double* cdf   = (double*)alloc((size_t)B * F * sizeof(double));
  double* bsum  = (double*)alloc((size_t)B * nc * sizeof(double));
  double* boffs = (double*)alloc((size_t)B * nc * sizeof(double));
  double* Rmat  = (double*)alloc((size_t)B * Vn * 9 * sizeof(double));
  float* samples   = (float*)alloc((size_t)B * S * 3 * sizeof(float));
  unsigned* rowmin = (unsigned*)alloc((size_t)2 * B * S * sizeof(unsigned));
  size_t zdoubles = (size_t)B * Vn * 3 + (size_t)B * Vn + (size_t)B * Vn * 9 + 8;
  double* zbase = (double*)alloc(zdoubles * sizeof(double));
  double* Lv    = zbase;
  double* rw    = Lv + (size_t)B * Vn * 3;
  double* Smat  = rw + (size_t)B * Vn;
  double* accum = Smat + (size_t)B * Vn * 9;
  // accum: [0]=chamfer sum, [1]=lap sum, [2]=target_len sum, [3]=edge sum, [4]=rigid sum

  hipMemsetAsync(zbase, 0, zdoubles * sizeof(double), stream);
  int nrm = 2 * B * S;
  kInitRowmin<<<(nrm + TPB - 1) / TPB, TPB, 0, stream>>>(rowmin, nrm);
  kFaceAreas<<<(B * F + TPB - 1) / TPB, TPB, 0, stream>>>(vscr, faces, cdf, B, Vn, F);
  kScan1<<<B * nc, 1024, 0, stream>>>(cdf, bsum, F, nc);
  kScan2<<<B, 1024, 0, stream>>>(bsum, boffs, nc);
  kScan3<<<B * nc, 1024, 0, stream>>>(cdf, boffs, F, nc);
  kSample<<<(B * S + TPB - 1) / TPB, TPB, 0, stream>>>(vscr, faces, cdf, rfu, rby,
                                                       samples, B, Vn, F, S);
  dim3 cg((S + TPB - 1) / TPB, 8, B);
  kChamfer<<<cg, TPB, 0, stream>>>(samples, trg, rowmin, S);
  kChamfer<<<cg, TPB, 0, stream>>>(trg, samples, rowmin + (size_t)B * S, S);
  kReduceRowmin<<<(nrm + TPB - 1) / TPB, TPB, 0, stream>>>(rowmin, nrm, accum + 0);
  kEdgeStd<<<(E + TPB - 1) / TPB, TPB, 0, stream>>>(vstd, edges, E, accum + 2);
  kEdgeLoss<<<(B * E + TPB - 1) / TPB, TPB, 0, stream>>>(vscr, edges, B, Vn, E,
                                                         accum + 2, accum + 3);
  kLapScatter<<<(B * F + TPB - 1) / TPB, TPB, 0, stream>>>(vscr, faces, Lv, rw, B, Vn, F);
  kLapNorm<<<(B * Vn + TPB - 1) / TPB, TPB, 0, stream>>>(vscr, Lv, rw, B, Vn, accum + 1);
  kRigidScatter<<<(B * F + TPB - 1) / TPB, TPB, 0, stream>>>(vstd, vscr, faces, Smat,
                                                             B, Vn, F);
  kRigidR<<<(B * Vn + TPB - 1) / TPB, TPB, 0, stream>>>(Smat, Rmat, B * Vn);
  kRigidRes<<<(B * F + TPB - 1) / TPB, TPB, 0, stream>>>(vstd, vscr, faces, Rmat,
                                                         B, Vn, F, accum + 4);
  kFinalize<<<1, 1, 0, stream>>>(accum, out, B, Vn, S, E);
}

// Round 2
// 289.199 us; speedup vs baseline: 1.6653x; 1.6653x over previous
//
#include <hip/hip_runtime.h>
#include <math.h>

#define TPB 256

static __device__ __forceinline__ void atomAddD(double* p, double v) {
  __hip_atomic_fetch_add(p, v, __ATOMIC_RELAXED, __HIP_MEMORY_SCOPE_AGENT);
}

static __device__ __forceinline__ double bredsum(double v) {
  __shared__ double sb[TPB];
  int t = threadIdx.x;
  sb[t] = v;
  __syncthreads();
  for (int o = TPB / 2; o > 0; o >>= 1) {
    if (t < o) sb[t] += sb[t + o];
    __syncthreads();
  }
  double r = sb[0];
  __syncthreads();
  return r;
}

// cot weights per corner, matching _cot_edges (Heron area with 1e-12 clip)
static __device__ __forceinline__ void faceCots(const double p0[3], const double p1[3],
                                                const double p2[3], double cot[3]) {
  double A2 = 0, B2 = 0, C2 = 0;
  for (int c = 0; c < 3; c++) {
    double d12 = p1[c] - p2[c]; A2 += d12 * d12;
    double d02 = p0[c] - p2[c]; B2 += d02 * d02;
    double d01 = p0[c] - p1[c]; C2 += d01 * d01;
  }
  double A = sqrt(A2), Bl = sqrt(B2), C = sqrt(C2);
  double s = 0.5 * (A + Bl + C);
  double pr = s * (s - A) * (s - Bl) * (s - C);
  pr = pr < 1e-12 ? 1e-12 : pr;
  double inv4 = 1.0 / (4.0 * sqrt(pr));
  cot[0] = (B2 + C2 - A2) * inv4;
  cot[1] = (A2 + C2 - B2) * inv4;
  cot[2] = (A2 + B2 - C2) * inv4;
}

// Kabsch rotation via Jacobi eigen of S^T S; det-flip handled by
// R = v1 u1^T + v2 u2^T + (v1 x v2)(u1 x u2)^T
static __device__ void kabschR(const double S[3][3], double R9[9]) {
  double A[3][3];
  for (int a = 0; a < 3; a++)
    for (int c = 0; c < 3; c++) {
      double t = 0;
      for (int r = 0; r < 3; r++) t += S[r][a] * S[r][c];
      A[a][c] = t;
    }
  double V[3][3] = {{1, 0, 0}, {0, 1, 0}, {0, 0, 1}};
  const int PP[3] = {0, 0, 1}, QQ[3] = {1, 2, 2};
  for (int sw = 0; sw < 12; sw++) {
    double off = fabs(A[0][1]) + fabs(A[0][2]) + fabs(A[1][2]);
    double dia = fabs(A[0][0]) + fabs(A[1][1]) + fabs(A[2][2]);
    if (!(off > dia * 1e-15)) break;
    for (int pi = 0; pi < 3; pi++) {
      int p = PP[pi], q = QQ[pi];
      double apq = A[p][q];
      if (apq == 0.0) continue;
      double app = A[p][p], aqq = A[q][q];
      double theta = (aqq - app) / (2.0 * apq);
      double t = 1.0 / (fabs(theta) + sqrt(theta * theta + 1.0));
      if (theta < 0.0) t = -t;
      double c = 1.0 / sqrt(t * t + 1.0), sn = t * c;
      A[p][p] = app - t * apq;
      A[q][q] = aqq + t * apq;
      A[p][q] = A[q][p] = 0.0;
      int r = 3 - p - q;
      double arp = A[r][p], arq = A[r][q];
      A[r][p] = A[p][r] = c * arp - sn * arq;
      A[r][q] = A[q][r] = sn * arp + c * arq;
      for (int k = 0; k < 3; k++) {
        double vkp = V[k][p], vkq = V[k][q];
        V[k][p] = c * vkp - sn * vkq;
        V[k][q] = sn * vkp + c * vkq;
      }
    }
  }
  double lam[3] = {A[0][0], A[1][1], A[2][2]};
  int o0 = 0, o1 = 1, o2 = 2;
  if (lam[o0] < lam[o1]) { int t = o0; o0 = o1; o1 = t; }
  if (lam[o0] < lam[o2]) { int t = o0; o0 = o2; o2 = t; }
  if (lam[o1] < lam[o2]) { int t = o1; o1 = o2; o2 = t; }
  double v1[3] = {V[0][o0], V[1][o0], V[2][o0]};
  double v2[3] = {V[0][o1], V[1][o1], V[2][o1]};
  double R[3][3] = {{1, 0, 0}, {0, 1, 0}, {0, 0, 1}};
  double b1[3], b2[3];
  for (int r = 0; r < 3; r++) {
    b1[r] = S[r][0] * v1[0] + S[r][1] * v1[1] + S[r][2] * v1[2];
    b2[r] = S[r][0] * v2[0] + S[r][1] * v2[1] + S[r][2] * v2[2];
  }
  double n1 = sqrt(b1[0] * b1[0] + b1[1] * b1[1] + b1[2] * b1[2]);
  if (n1 > 1e-300 && isfinite(n1)) {
    double u1[3] = {b1[0] / n1, b1[1] / n1, b1[2] / n1};
    double dp = u1[0] * b2[0] + u1[1] * b2[1] + u1[2] * b2[2];
    for (int r = 0; r < 3; r++) b2[r] -= dp * u1[r];
    double n2 = sqrt(b2[0] * b2[0] + b2[1] * b2[1] + b2[2] * b2[2]);
    double u2[3];
    if (n2 > n1 * 1e-14) {
      u2[0] = b2[0] / n2; u2[1] = b2[1] / n2; u2[2] = b2[2] / n2;
    } else {
      int k = 0;
      if (fabs(u1[1]) < fabs(u1[k])) k = 1;
      if (fabs(u1[2]) < fabs(u1[k])) k = 2;
      double e0 = (k == 0) - u1[k] * u1[0];
      double e1 = (k == 1) - u1[k] * u1[1];
      double e2 = (k == 2) - u1[k] * u1[2];
      double nw = sqrt(e0 * e0 + e1 * e1 + e2 * e2);
      u2[0] = e0 / nw; u2[1] = e1 / nw; u2[2] = e2 / nw;
    }
    double u3[3] = {u1[1] * u2[2] - u1[2] * u2[1],
                    u1[2] * u2[0] - u1[0] * u2[2],
                    u1[0] * u2[1] - u1[1] * u2[0]};
    double w3[3] = {v1[1] * v2[2] - v1[2] * v2[1],
                    v1[2] * v2[0] - v1[0] * v2[2],
                    v1[0] * v2[1] - v1[1] * v2[0]};
    for (int r = 0; r < 3; r++)
      for (int c = 0; c < 3; c++)
        R[r][c] = v1[r] * u1[c] + v2[r] * u2[c] + w3[r] * u3[c];
  }
  for (int r = 0; r < 3; r++)
    for (int c = 0; c < 3; c++) R9[r * 3 + c] = R[r][c];
}

static __device__ __forceinline__ double resid(const double* R, const double* es,
                                               const double* ec) {
  double r0 = ec[0] - (R[0] * es[0] + R[1] * es[1] + R[2] * es[2]);
  double r1 = ec[1] - (R[3] * es[0] + R[4] * es[1] + R[5] * es[2]);
  double r2 = ec[2] - (R[6] * es[0] + R[7] * es[1] + R[8] * es[2]);
  return r0 * r0 + r1 * r1 + r2 * r2;
}

__global__ void kInitRowmin(unsigned* rm, int n) {
  int i = blockIdx.x * blockDim.x + threadIdx.x;
  if (i < n) rm[i] = 0x7f800000u;  // +inf
}

__global__ void kFaceAreas(const float* verts, const int* faces, double* areas,
                           int B, int Vn, int F) {
  int i = blockIdx.x * blockDim.x + threadIdx.x;
  if (i >= B * F) return;
  int b = i / F, f = i % F;
  const float* vb = verts + (size_t)b * Vn * 3;
  int i0 = faces[f * 3], i1 = faces[f * 3 + 1], i2 = faces[f * 3 + 2];
  double ax = (double)vb[i1 * 3 + 0] - vb[i0 * 3 + 0];
  double ay = (double)vb[i1 * 3 + 1] - vb[i0 * 3 + 1];
  double az = (double)vb[i1 * 3 + 2] - vb[i0 * 3 + 2];
  double bx = (double)vb[i2 * 3 + 0] - vb[i0 * 3 + 0];
  double by = (double)vb[i2 * 3 + 1] - vb[i0 * 3 + 1];
  double bz = (double)vb[i2 * 3 + 2] - vb[i0 * 3 + 2];
  double cx = ay * bz - az * by;
  double cy = az * bx - ax * bz;
  double cz = ax * by - ay * bx;
  areas[i] = 0.5 * sqrt(cx * cx + cy * cy + cz * cz);
}

// two-level inclusive scan over F doubles per batch (chunk = 1024)
__global__ void kScan1(double* a, double* bsum, int F, int nc) {
  int blk = blockIdx.x;
  int b = blk / nc, c = blk % nc;
  int t = threadIdx.x;
  int f = c * 1024 + t;
  __shared__ double s[1024];
  double v = (f < F) ? a[(size_t)b * F + f] : 0.0;
  s[t] = v;
  __syncthreads();
  for (int o = 1; o < 1024; o <<= 1) {
    double ad = (t >= o) ? s[t - o] : 0.0;
    __syncthreads();
    s[t] += ad;
    __syncthreads();
  }
  if (f < F) a[(size_t)b * F + f] = s[t];
  if (t == 1023) bsum[(size_t)b * nc + c] = s[1023];
}

__global__ void kScan2(const double* bsum, double* boffs, int nc) {
  int b = blockIdx.x, t = threadIdx.x;
  __shared__ double s[1024];
  double v = (t < nc) ? bsum[(size_t)b * nc + t] : 0.0;
  s[t] = v;
  __syncthreads();
  for (int o = 1; o < 1024; o <<= 1) {
    double ad = (t >= o) ? s[t - o] : 0.0;
    __syncthreads();
    s[t] += ad;
    __syncthreads();
  }
  if (t < nc) boffs[(size_t)b * nc + t] = s[t] - v;  // exclusive
}

__global__ void kScan3(double* a, const double* boffs, int F, int nc) {
  int blk = blockIdx.x;
  int b = blk / nc, c = blk % nc;
  int f = c * 1024 + threadIdx.x;
  if (f < F) a[(size_t)b * F + f] += boffs[(size_t)b * nc + c];
}

__global__ void kSample(const float* verts, const int* faces, const double* cdf,
                        const float* rfu, const float* rbary, float* samples,
                        int B, int Vn, int F, int S) {
  int i = blockIdx.x * blockDim.x + threadIdx.x;
  if (i >= B * S) return;
  int b = i / S;
  const double* c = cdf + (size_t)b * F;
  double total = c[F - 1];
  double tgt = (double)rfu[i] * total;
  int lo = 0, hi = F;  // lower_bound: first idx with cdf[idx] >= tgt
  while (lo < hi) {
    int m = (lo + hi) >> 1;
    if (c[m] < tgt) lo = m + 1; else hi = m;
  }
  int f = lo < F ? lo : F - 1;
  const float* vb = verts + (size_t)b * Vn * 3;
  int i0 = faces[f * 3], i1 = faces[f * 3 + 1], i2 = faces[f * 3 + 2];
  float r0 = rbary[(size_t)i * 2], r1 = rbary[(size_t)i * 2 + 1];
  float su = sqrtf(r0);
  float w0 = 1.f - su, w1 = su * (1.f - r1), w2 = su * r1;
  samples[(size_t)i * 3 + 0] = w0 * vb[i0 * 3 + 0] + w1 * vb[i1 * 3 + 0] + w2 * vb[i2 * 3 + 0];
  samples[(size_t)i * 3 + 1] = w0 * vb[i0 * 3 + 1] + w1 * vb[i1 * 3 + 1] + w2 * vb[i2 * 3 + 1];
  samples[(size_t)i * 3 + 2] = w0 * vb[i0 * 3 + 2] + w1 * vb[i1 * 3 + 2] + w2 * vb[i2 * 3 + 2];
}

// row-mins of the SxS pairwise sq-dist matrix; grid (i-tiles, j-tiles, B)
__global__ void kChamfer(const float* X, const float* Y, unsigned* rowmin, int S) {
  int b = blockIdx.z;
  int i = blockIdx.x * TPB + threadIdx.x;
  int j0 = blockIdx.y * TPB;
  int n = min(TPB, S - j0);
  __shared__ float4 sy[TPB];
  const float* Yb = Y + ((size_t)b * S + j0) * 3;
  if ((int)threadIdx.x < n) {
    int t = threadIdx.x;
    sy[t] = make_float4(Yb[t * 3], Yb[t * 3 + 1], Yb[t * 3 + 2], 0.f);
  }
  __syncthreads();
  if (i >= S) return;
  const float* Xb = X + (size_t)b * S * 3;
  float x0 = Xb[i * 3], x1 = Xb[i * 3 + 1], x2 = Xb[i * 3 + 2];
  float inf = __int_as_float(0x7f800000);
  float m0 = inf, m1 = inf, m2 = inf, m3 = inf;
  int k = 0;
  for (; k + 4 <= n; k += 4) {
    float4 y0 = sy[k], y1 = sy[k + 1], y2 = sy[k + 2], y3 = sy[k + 3];
    float a0 = x0 - y0.x, b0 = x1 - y0.y, c0 = x2 - y0.z;
    float a1 = x0 - y1.x, b1 = x1 - y1.y, c1 = x2 - y1.z;
    float a2 = x0 - y2.x, b2 = x1 - y2.y, c2 = x2 - y2.z;
    float a3 = x0 - y3.x, b3 = x1 - y3.y, c3 = x2 - y3.z;
    m0 = fminf(m0, a0 * a0 + b0 * b0 + c0 * c0);
    m1 = fminf(m1, a1 * a1 + b1 * b1 + c1 * c1);
    m2 = fminf(m2, a2 * a2 + b2 * b2 + c2 * c2);
    m3 = fminf(m3, a3 * a3 + b3 * b3 + c3 * c3);
  }
  for (; k < n; k++) {
    float4 y = sy[k];
    float a = x0 - y.x, bb = x1 - y.y, cc = x2 - y.z;
    m0 = fminf(m0, a * a + bb * bb + cc * cc);
  }
  float mn = fminf(fminf(m0, m1), fminf(m2, m3));
  atomicMin(&rowmin[(size_t)b * S + i], __float_as_uint(mn));
}

__global__ void kReduceRowmin(const unsigned* rm, int n, double* acc) {
  int i = blockIdx.x * TPB + threadIdx.x;
  double v = 0.0;
  if (i < n) v = (double)__uint_as_float(rm[i]);
  double r = bredsum(v);
  if (threadIdx.x == 0) atomAddD(acc, r);
}

__global__ void kEdgeStd(const float* vstd, const int* edges, int E, double* acc) {
  int i = blockIdx.x * TPB + threadIdx.x;
  double val = 0.0;
  if (i < E) {
    int e0 = edges[(size_t)i * 2], e1 = edges[(size_t)i * 2 + 1];
    double dx = (double)vstd[e0 * 3 + 0] - vstd[e1 * 3 + 0];
    double dy = (double)vstd[e0 * 3 + 1] - vstd[e1 * 3 + 1];
    double dz = (double)vstd[e0 * 3 + 2] - vstd[e1 * 3 + 2];
    val = sqrt(dx * dx + dy * dy + dz * dz);
  }
  double r = bredsum(val);
  if (threadIdx.x == 0) atomAddD(acc, r);
}

__global__ void kEdgeLoss(const float* vscr, const int* edges, int B, int Vn, int E,
                          const double* tacc, double* acc) {
  int i = blockIdx.x * TPB + threadIdx.x;
  double tl = tacc[0] / (double)E;
  double val = 0.0;
  if (i < B * E) {
    int b = i / E, e = i % E;
    const float* vb = vscr + (size_t)b * Vn * 3;
    int e0 = edges[(size_t)e * 2], e1 = edges[(size_t)e * 2 + 1];
    double dx = (double)vb[e0 * 3 + 0] - vb[e1 * 3 + 0];
    double dy = (double)vb[e0 * 3 + 1] - vb[e1 * 3 + 1];
    double dz = (double)vb[e0 * 3 + 2] - vb[e1 * 3 + 2];
    double l = sqrt(dx * dx + dy * dy + dz * dz);
    double d = l - tl;
    val = d * d;
  }
  double r = bredsum(val);
  if (threadIdx.x == 0) atomAddD(acc, r);
}

// ---- vertex->(face,corner) CSR adjacency ----
__global__ void kAdjCount(const int* faces, int* deg, int F) {
  int f = blockIdx.x * TPB + threadIdx.x;
  if (f >= F) return;
  atomicAdd(&deg[faces[f * 3 + 0]], 1);
  atomicAdd(&deg[faces[f * 3 + 1]], 1);
  atomicAdd(&deg[faces[f * 3 + 2]], 1);
}

__global__ void kAdjScan(const int* deg, int* rowstart, int Vn) {
  __shared__ int s[1024];
  int t = threadIdx.x;
  int ch = (Vn + 1023) / 1024;
  int begin = t * ch;
  int end = begin + ch; if (end > Vn) end = Vn;
  int sum = 0;
  for (int i = begin; i < end; i++) sum += deg[i];
  s[t] = sum;
  __syncthreads();
  for (int o = 1; o < 1024; o <<= 1) {
    int ad = (t >= o) ? s[t - o] : 0;
    __syncthreads();
    s[t] += ad;
    __syncthreads();
  }
  int run = s[t] - sum;  // exclusive prefix of this chunk
  for (int i = begin; i < end; i++) { rowstart[i] = run; run += deg[i]; }
  if (t == 1023) rowstart[Vn] = s[1023];
}

__global__ void kAdjFill(const int* faces, const int* rowstart, int* pos, int* adj, int F) {
  int f = blockIdx.x * TPB + threadIdx.x;
  if (f >= F) return;
  for (int c = 0; c < 3; c++) {
    int v = faces[f * 3 + c];
    int slot = atomicAdd(&pos[v], 1);
    adj[rowstart[v] + slot] = (f << 2) | c;
  }
}

// ---- fused per-vertex gather: Laplacian + ARAP (S, R, residual) ----
__global__ void kVertexFused(const float* vstd, const float* vscr, const int* faces,
                             const int* rowstart, const int* adj, int B, int Vn,
                             double* accLap, double* accRigid) {
  int idx = blockIdx.x * TPB + threadIdx.x;
  double vlap = 0.0, vrig = 0.0;
  if (idx < B * Vn) {
    int b = idx / Vn, v = idx % Vn;
    const float* cb = vscr + (size_t)b * Vn * 3;
    int s0 = rowstart[v], s1 = rowstart[v + 1];
    double S[3][3] = {{0, 0, 0}, {0, 0, 0}, {0, 0, 0}};
    double Lv[3] = {0, 0, 0};
    double rw = 0.0;
    for (int k = s0; k < s1; k++) {
      int code = adj[k];
      int f = code >> 2, c = code & 3;
      int vi0 = faces[f * 3], vi1 = faces[f * 3 + 1], vi2 = faces[f * 3 + 2];
      double ps[3][3], pc[3][3];
      for (int d = 0; d < 3; d++) {
        ps[0][d] = vstd[vi0 * 3 + d]; ps[1][d] = vstd[vi1 * 3 + d]; ps[2][d] = vstd[vi2 * 3 + d];
        pc[0][d] = cb[vi0 * 3 + d];   pc[1][d] = cb[vi1 * 3 + d];   pc[2][d] = cb[vi2 * 3 + d];
      }
      double cs[3], cc[3];
      faceCots(ps[0], ps[1], ps[2], cs);   // std cots (rigid)
      faceCots(pc[0], pc[1], pc[2], cc);   // scr cots (laplacian)
      int o1 = (c == 2) ? 0 : c + 1;
      int o2 = (c == 0) ? 2 : c - 1;
      // Laplacian: edge (c,o1) has weight cot[o2]; edge (c,o2) has weight cot[o1]
      for (int d = 0; d < 3; d++)
        Lv[d] += cc[o2] * pc[o1][d] + cc[o1] * pc[o2][d];
      rw += cc[o1] + cc[o2];
      // ARAP S: rows from std edges, cols from scr edges
      double e1s[3], e1c[3], e2s[3], e2c[3];
      for (int d = 0; d < 3; d++) {
        e1s[d] = ps[c][d] - ps[o1][d]; e1c[d] = pc[c][d] - pc[o1][d];
        e2s[d] = ps[c][d] - ps[o2][d]; e2c[d] = pc[c][d] - pc[o2][d];
      }
      for (int r = 0; r < 3; r++)
        for (int c2 = 0; c2 < 3; c2++)
          S[r][c2] += cs[o2] * e1s[r] * e1c[c2] + cs[o1] * e2s[r] * e2c[c2];
    }
    // Laplacian norm term
    {
      double inv = (rw > 0.0) ? 1.0 / fmax(rw, 1e-12) : 0.0;
      double dx = Lv[0] * inv - (double)cb[v * 3 + 0];
      double dy = Lv[1] * inv - (double)cb[v * 3 + 1];
      double dz = Lv[2] * inv - (double)cb[v * 3 + 2];
      vlap = sqrt(dx * dx + dy * dy + dz * dz);
    }
    // Rotation
    double R9[9];
    kabschR(S, R9);
    // Rigid residual gather (recompute per-face data)
    for (int k = s0; k < s1; k++) {
      int code = adj[k];
      int f = code >> 2, c = code & 3;
      int vi0 = faces[f * 3], vi1 = faces[f * 3 + 1], vi2 = faces[f * 3 + 2];
      double ps[3][3], pc[3][3];
      for (int d = 0; d < 3; d++) {
        ps[0][d] = vstd[vi0 * 3 + d]; ps[1][d] = vstd[vi1 * 3 + d]; ps[2][d] = vstd[vi2 * 3 + d];
        pc[0][d] = cb[vi0 * 3 + d];   pc[1][d] = cb[vi1 * 3 + d];   pc[2][d] = cb[vi2 * 3 + d];
      }
      double cs[3];
      faceCots(ps[0], ps[1], ps[2], cs);
      int o1 = (c == 2) ? 0 : c + 1;
      int o2 = (c == 0) ? 2 : c - 1;
      double e1s[3], e1c[3], e2s[3], e2c[3];
      for (int d = 0; d < 3; d++) {
        e1s[d] = ps[c][d] - ps[o1][d]; e1c[d] = pc[c][d] - pc[o1][d];
        e2s[d] = ps[c][d] - ps[o2][d]; e2c[d] = pc[c][d] - pc[o2][d];
      }
      vrig += cs[o2] * resid(R9, e1s, e1c) + cs[o1] * resid(R9, e2s, e2c);
    }
  }
  double r1 = bredsum(vlap);
  if (threadIdx.x == 0) atomAddD(accLap, r1);
  double r2 = bredsum(vrig);
  if (threadIdx.x == 0) atomAddD(accRigid, r2);
}

__global__ void kFinalize(const double* acc, float* out, int B, int Vn, int S, int E) {
  if (blockIdx.x == 0 && threadIdx.x == 0) {
    out[0] = (float)(acc[0] / ((double)B * S));   // loss_p0 (both directions summed)
    out[1] = 1e-5f;                               // loss_n1
    out[2] = (float)(acc[1] / ((double)B * Vn));  // loss_lap
    out[3] = (float)(acc[3] / ((double)B * E));   // loss_edge
    out[4] = (float)(acc[4] / ((double)B * Vn));  // loss_rigid
  }
}

extern "C" void kernel_launch(void* const* d_in, const int* in_sizes, int n_in,
                              void* d_out, int out_size, void* d_ws, size_t ws_size,
                              hipStream_t stream) {
  const float* vscr = (const float*)d_in[0];
  const float* vstd = (const float*)d_in[1];
  const float* trg  = (const float*)d_in[2];
  const float* rfu  = (const float*)d_in[3];
  const float* rby  = (const float*)d_in[4];
  const int* faces  = (const int*)d_in[5];
  const int* edges  = (const int*)d_in[6];
  float* out = (float*)d_out;

  int nVs = in_sizes[1];
  int Vn = nVs / 3;
  int B = in_sizes[0] / nVs;
  int S = in_sizes[3] / B;
  int F = in_sizes[5] / 3;
  int E = in_sizes[6] / 2;
  int nc = (F + 1023) / 1024;

  char* p = (char*)d_ws;
  auto alloc = [&](size_t bytes) -> void* {
    void* r = (void*)p;
    p += (bytes + 255) & ~(size_t)255;
    return r;
  };
  double* cdf   = (double*)alloc((size_t)B * F * sizeof(double));
  double* bsum  = (double*)alloc((size_t)B * nc * sizeof(double));
  double* boffs = (double*)alloc((size_t)B * nc * sizeof(double));
  float* samples   = (float*)alloc((size_t)B * S * 3 * sizeof(float));
  unsigned* rowmin = (unsigned*)alloc((size_t)2 * B * S * sizeof(unsigned));
  int* degpos   = (int*)alloc((size_t)2 * Vn * sizeof(int));   // deg | pos (zeroed)
  int* deg      = degpos;
  int* pos      = degpos + Vn;
  int* rowstart = (int*)alloc((size_t)(Vn + 1) * sizeof(int));
  int* adj      = (int*)alloc((size_t)3 * F * sizeof(int));
  double* accum = (double*)alloc(8 * sizeof(double));
  // accum: [0]=chamfer sum, [1]=lap sum, [2]=target_len sum, [3]=edge sum, [4]=rigid sum

  hipMemsetAsync(degpos, 0, (size_t)2 * Vn * sizeof(int), stream);
  hipMemsetAsync(accum, 0, 8 * sizeof(double), stream);

  int nrm = 2 * B * S;
  kInitRowmin<<<(nrm + TPB - 1) / TPB, TPB, 0, stream>>>(rowmin, nrm);

  // adjacency build
  kAdjCount<<<(F + TPB - 1) / TPB, TPB, 0, stream>>>(faces, deg, F);
  kAdjScan<<<1, 1024, 0, stream>>>(deg, rowstart, Vn);
  kAdjFill<<<(F + TPB - 1) / TPB, TPB, 0, stream>>>(faces, rowstart, pos, adj, F);

  // sampling + chamfer
  kFaceAreas<<<(B * F + TPB - 1) / TPB, TPB, 0, stream>>>(vscr, faces, cdf, B, Vn, F);
  kScan1<<<B * nc, 1024, 0, stream>>>(cdf, bsum, F, nc);
  kScan2<<<B, 1024, 0, stream>>>(bsum, boffs, nc);
  kScan3<<<B * nc, 1024, 0, stream>>>(cdf, boffs, F, nc);
  kSample<<<(B * S + TPB - 1) / TPB, TPB, 0, stream>>>(vscr, faces, cdf, rfu, rby,
                                                       samples, B, Vn, F, S);
  dim3 cg((S + TPB - 1) / TPB, (S + TPB - 1) / TPB, B);
  kChamfer<<<cg, TPB, 0, stream>>>(samples, trg, rowmin, S);
  kChamfer<<<cg, TPB, 0, stream>>>(trg, samples, rowmin + (size_t)B * S, S);
  kReduceRowmin<<<(nrm + TPB - 1) / TPB, TPB, 0, stream>>>(rowmin, nrm, accum + 0);

  // edge losses
  kEdgeStd<<<(E + TPB - 1) / TPB, TPB, 0, stream>>>(vstd, edges, E, accum + 2);
  kEdgeLoss<<<(B * E + TPB - 1) / TPB, TPB, 0, stream>>>(vscr, edges, B, Vn, E,
                                                         accum + 2, accum + 3);

  // fused laplacian + rigid
  kVertexFused<<<(B * Vn + TPB - 1) / TPB, TPB, 0, stream>>>(vstd, vscr, faces,
                                                             rowstart, adj, B, Vn,
                                                             accum + 1, accum + 4);

  kFinalize<<<1, 1, 0, stream>>>(accum, out, B, Vn, S, E);
}

// Round 3
// 263.337 us; speedup vs baseline: 1.8289x; 1.0982x over previous
//
#include <hip/hip_runtime.h>
#include <math.h>

#define TPB 256

static __device__ __forceinline__ void atomAddD(double* p, double v) {
  __hip_atomic_fetch_add(p, v, __ATOMIC_RELAXED, __HIP_MEMORY_SCOPE_AGENT);
}

static __device__ __forceinline__ double bredsum(double v) {
  __shared__ double sb[TPB];
  int t = threadIdx.x;
  sb[t] = v;
  __syncthreads();
  for (int o = TPB / 2; o > 0; o >>= 1) {
    if (t < o) sb[t] += sb[t + o];
    __syncthreads();
  }
  double r = sb[0];
  __syncthreads();
  return r;
}

// one Jacobi rotation, all indices compile-time -> stays in registers
template <int p, int q, int r>
static __device__ __forceinline__ void jrot(double A[3][3], double V[3][3]) {
  double apq = A[p][q];
  if (apq == 0.0) return;
  double app = A[p][p], aqq = A[q][q];
  double theta = (aqq - app) / (2.0 * apq);
  double t = 1.0 / (fabs(theta) + sqrt(theta * theta + 1.0));
  if (theta < 0.0) t = -t;
  double c = 1.0 / sqrt(t * t + 1.0), sn = t * c;
  A[p][p] = app - t * apq;
  A[q][q] = aqq + t * apq;
  A[p][q] = 0.0;
  A[q][p] = 0.0;
  double arp = A[r][p], arq = A[r][q];
  A[r][p] = c * arp - sn * arq; A[p][r] = A[r][p];
  A[r][q] = sn * arp + c * arq; A[q][r] = A[r][q];
#pragma unroll
  for (int k = 0; k < 3; k++) {
    double vkp = V[k][p], vkq = V[k][q];
    V[k][p] = c * vkp - sn * vkq;
    V[k][q] = sn * vkp + c * vkq;
  }
}

#define ESWAP(la, lax, lay, laz, lb, lbx, lby, lbz)                       \
  if (la < lb) {                                                          \
    double t_;                                                            \
    t_ = la; la = lb; lb = t_;                                            \
    t_ = lax; lax = lbx; lbx = t_;                                        \
    t_ = lay; lay = lby; lby = t_;                                        \
    t_ = laz; laz = lbz; lbz = t_;                                        \
  }

// Kabsch rotation via Jacobi eigen of S^T S; det-flip handled by
// R = v1 u1^T + v2 u2^T + (v1 x v2)(u1 x u2)^T   (all static indexing)
static __device__ void kabschR(const double S[3][3], double R9[9]) {
  double A[3][3];
#pragma unroll
  for (int a = 0; a < 3; a++)
#pragma unroll
    for (int c = 0; c < 3; c++)
      A[a][c] = S[0][a] * S[0][c] + S[1][a] * S[1][c] + S[2][a] * S[2][c];
  double V[3][3] = {{1, 0, 0}, {0, 1, 0}, {0, 0, 1}};
  for (int sw = 0; sw < 12; sw++) {
    double off = fabs(A[0][1]) + fabs(A[0][2]) + fabs(A[1][2]);
    double dia = fabs(A[0][0]) + fabs(A[1][1]) + fabs(A[2][2]);
    if (!(off > dia * 1e-15)) break;
    jrot<0, 1, 2>(A, V);
    jrot<0, 2, 1>(A, V);
    jrot<1, 2, 0>(A, V);
  }
  double l0 = A[0][0], l1 = A[1][1], l2 = A[2][2];
  double a0x = V[0][0], a0y = V[1][0], a0z = V[2][0];
  double a1x = V[0][1], a1y = V[1][1], a1z = V[2][1];
  double a2x = V[0][2], a2y = V[1][2], a2z = V[2][2];
  ESWAP(l0, a0x, a0y, a0z, l1, a1x, a1y, a1z);
  ESWAP(l0, a0x, a0y, a0z, l2, a2x, a2y, a2z);
  ESWAP(l1, a1x, a1y, a1z, l2, a2x, a2y, a2z);
  double R00 = 1, R01 = 0, R02 = 0, R10 = 0, R11 = 1, R12 = 0, R20 = 0, R21 = 0, R22 = 1;
  double b1x = S[0][0] * a0x + S[0][1] * a0y + S[0][2] * a0z;
  double b1y = S[1][0] * a0x + S[1][1] * a0y + S[1][2] * a0z;
  double b1z = S[2][0] * a0x + S[2][1] * a0y + S[2][2] * a0z;
  double b2x = S[0][0] * a1x + S[0][1] * a1y + S[0][2] * a1z;
  double b2y = S[1][0] * a1x + S[1][1] * a1y + S[1][2] * a1z;
  double b2z = S[2][0] * a1x + S[2][1] * a1y + S[2][2] * a1z;
  double n1 = sqrt(b1x * b1x + b1y * b1y + b1z * b1z);
  if (n1 > 1e-300 && isfinite(n1)) {
    double u1x = b1x / n1, u1y = b1y / n1, u1z = b1z / n1;
    double dp = u1x * b2x + u1y * b2y + u1z * b2z;
    b2x -= dp * u1x; b2y -= dp * u1y; b2z -= dp * u1z;
    double n2 = sqrt(b2x * b2x + b2y * b2y + b2z * b2z);
    double u2x, u2y, u2z;
    if (n2 > n1 * 1e-14) {
      u2x = b2x / n2; u2y = b2y / n2; u2z = b2z / n2;
    } else {
      double f0 = fabs(u1x), f1 = fabs(u1y), f2 = fabs(u1z);
      double e0, e1, e2;
      if (f0 <= f1 && f0 <= f2) { e0 = 1.0 - u1x * u1x; e1 = -u1x * u1y; e2 = -u1x * u1z; }
      else if (f1 <= f2)        { e0 = -u1y * u1x; e1 = 1.0 - u1y * u1y; e2 = -u1y * u1z; }
      else                      { e0 = -u1z * u1x; e1 = -u1z * u1y; e2 = 1.0 - u1z * u1z; }
      double nw = sqrt(e0 * e0 + e1 * e1 + e2 * e2);
      u2x = e0 / nw; u2y = e1 / nw; u2z = e2 / nw;
    }
    double u3x = u1y * u2z - u1z * u2y;
    double u3y = u1z * u2x - u1x * u2z;
    double u3z = u1x * u2y - u1y * u2x;
    double w3x = a0y * a1z - a0z * a1y;
    double w3y = a0z * a1x - a0x * a1z;
    double w3z = a0x * a1y - a0y * a1x;
    R00 = a0x * u1x + a1x * u2x + w3x * u3x;
    R01 = a0x * u1y + a1x * u2y + w3x * u3y;
    R02 = a0x * u1z + a1x * u2z + w3x * u3z;
    R10 = a0y * u1x + a1y * u2x + w3y * u3x;
    R11 = a0y * u1y + a1y * u2y + w3y * u3y;
    R12 = a0y * u1z + a1y * u2z + w3y * u3z;
    R20 = a0z * u1x + a1z * u2x + w3z * u3x;
    R21 = a0z * u1y + a1z * u2y + w3z * u3y;
    R22 = a0z * u1z + a1z * u2z + w3z * u3z;
  }
  R9[0] = R00; R9[1] = R01; R9[2] = R02;
  R9[3] = R10; R9[4] = R11; R9[5] = R12;
  R9[6] = R20; R9[7] = R21; R9[8] = R22;
}

static __device__ __forceinline__ double resid(const double* R, const double* es,
                                               const double* ec) {
  double r0 = ec[0] - (R[0] * es[0] + R[1] * es[1] + R[2] * es[2]);
  double r1 = ec[1] - (R[3] * es[0] + R[4] * es[1] + R[5] * es[2]);
  double r2 = ec[2] - (R[6] * es[0] + R[7] * es[1] + R[8] * es[2]);
  return r0 * r0 + r1 * r1 + r2 * r2;
}

__global__ void kInitRowmin(unsigned* rm, int n) {
  int i = blockIdx.x * blockDim.x + threadIdx.x;
  if (i < n) rm[i] = 0x7f800000u;  // +inf
}

// per-(b,f): sampling area (cross product) + scr cots (Heron, matching reference)
__global__ void kFacePrepScr(const float* verts, const int* faces, double* areas,
                             double* ccot, int B, int Vn, int F) {
  int i = blockIdx.x * blockDim.x + threadIdx.x;
  if (i >= B * F) return;
  int b = i / F, f = i % F;
  const float* vb = verts + (size_t)b * Vn * 3;
  int i0 = faces[f * 3], i1 = faces[f * 3 + 1], i2 = faces[f * 3 + 2];
  double p0x = vb[i0 * 3], p0y = vb[i0 * 3 + 1], p0z = vb[i0 * 3 + 2];
  double p1x = vb[i1 * 3], p1y = vb[i1 * 3 + 1], p1z = vb[i1 * 3 + 2];
  double p2x = vb[i2 * 3], p2y = vb[i2 * 3 + 1], p2z = vb[i2 * 3 + 2];
  double ax = p1x - p0x, ay = p1y - p0y, az = p1z - p0z;
  double bx = p2x - p0x, by = p2y - p0y, bz = p2z - p0z;
  double cx = ay * bz - az * by, cy = az * bx - ax * bz, cz = ax * by - ay * bx;
  areas[i] = 0.5 * sqrt(cx * cx + cy * cy + cz * cz);
  double dx = p1x - p2x, dy = p1y - p2y, dz = p1z - p2z;
  double A2 = dx * dx + dy * dy + dz * dz;
  double B2 = bx * bx + by * by + bz * bz;
  double C2 = ax * ax + ay * ay + az * az;
  double A = sqrt(A2), Bl = sqrt(B2), C = sqrt(C2);
  double s = 0.5 * (A + Bl + C);
  double pr = s * (s - A) * (s - Bl) * (s - C);
  pr = pr < 1e-12 ? 1e-12 : pr;
  double inv4 = 1.0 / (4.0 * sqrt(pr));
  ccot[(size_t)i * 3 + 0] = (B2 + C2 - A2) * inv4;
  ccot[(size_t)i * 3 + 1] = (A2 + C2 - B2) * inv4;
  ccot[(size_t)i * 3 + 2] = (A2 + B2 - C2) * inv4;
}

__global__ void kFacePrepStd(const float* vstd, const int* faces, double* scot, int F) {
  int f = blockIdx.x * blockDim.x + threadIdx.x;
  if (f >= F) return;
  int i0 = faces[f * 3], i1 = faces[f * 3 + 1], i2 = faces[f * 3 + 2];
  double p0x = vstd[i0 * 3], p0y = vstd[i0 * 3 + 1], p0z = vstd[i0 * 3 + 2];
  double p1x = vstd[i1 * 3], p1y = vstd[i1 * 3 + 1], p1z = vstd[i1 * 3 + 2];
  double p2x = vstd[i2 * 3], p2y = vstd[i2 * 3 + 1], p2z = vstd[i2 * 3 + 2];
  double ax = p1x - p0x, ay = p1y - p0y, az = p1z - p0z;
  double bx = p2x - p0x, by = p2y - p0y, bz = p2z - p0z;
  double dx = p1x - p2x, dy = p1y - p2y, dz = p1z - p2z;
  double A2 = dx * dx + dy * dy + dz * dz;
  double B2 = bx * bx + by * by + bz * bz;
  double C2 = ax * ax + ay * ay + az * az;
  double A = sqrt(A2), Bl = sqrt(B2), C = sqrt(C2);
  double s = 0.5 * (A + Bl + C);
  double pr = s * (s - A) * (s - Bl) * (s - C);
  pr = pr < 1e-12 ? 1e-12 : pr;
  double inv4 = 1.0 / (4.0 * sqrt(pr));
  scot[(size_t)f * 3 + 0] = (B2 + C2 - A2) * inv4;
  scot[(size_t)f * 3 + 1] = (A2 + C2 - B2) * inv4;
  scot[(size_t)f * 3 + 2] = (A2 + B2 - C2) * inv4;
}

// two-level inclusive scan over F doubles per batch (chunk = 1024)
__global__ void kScan1(double* a, double* bsum, int F, int nc) {
  int blk = blockIdx.x;
  int b = blk / nc, c = blk % nc;
  int t = threadIdx.x;
  int f = c * 1024 + t;
  __shared__ double s[1024];
  double v = (f < F) ? a[(size_t)b * F + f] : 0.0;
  s[t] = v;
  __syncthreads();
  for (int o = 1; o < 1024; o <<= 1) {
    double ad = (t >= o) ? s[t - o] : 0.0;
    __syncthreads();
    s[t] += ad;
    __syncthreads();
  }
  if (f < F) a[(size_t)b * F + f] = s[t];
  if (t == 1023) bsum[(size_t)b * nc + c] = s[1023];
}

__global__ void kScan2(const double* bsum, double* boffs, int nc) {
  int b = blockIdx.x, t = threadIdx.x;
  __shared__ double s[1024];
  double v = (t < nc) ? bsum[(size_t)b * nc + t] : 0.0;
  s[t] = v;
  __syncthreads();
  for (int o = 1; o < 1024; o <<= 1) {
    double ad = (t >= o) ? s[t - o] : 0.0;
    __syncthreads();
    s[t] += ad;
    __syncthreads();
  }
  if (t < nc) boffs[(size_t)b * nc + t] = s[t] - v;  // exclusive
}

__global__ void kScan3(double* a, const double* boffs, int F, int nc) {
  int blk = blockIdx.x;
  int b = blk / nc, c = blk % nc;
  int f = c * 1024 + threadIdx.x;
  if (f < F) a[(size_t)b * F + f] += boffs[(size_t)b * nc + c];
}

__global__ void kSample(const float* verts, const int* faces, const double* cdf,
                        const float* rfu, const float* rbary, float* samples,
                        int B, int Vn, int F, int S) {
  int i = blockIdx.x * blockDim.x + threadIdx.x;
  if (i >= B * S) return;
  int b = i / S;
  const double* c = cdf + (size_t)b * F;
  double total = c[F - 1];
  double tgt = (double)rfu[i] * total;
  int lo = 0, hi = F;
  while (lo < hi) {
    int m = (lo + hi) >> 1;
    if (c[m] < tgt) lo = m + 1; else hi = m;
  }
  int f = lo < F ? lo : F - 1;
  const float* vb = verts + (size_t)b * Vn * 3;
  int i0 = faces[f * 3], i1 = faces[f * 3 + 1], i2 = faces[f * 3 + 2];
  float r0 = rbary[(size_t)i * 2], r1 = rbary[(size_t)i * 2 + 1];
  float su = sqrtf(r0);
  float w0 = 1.f - su, w1 = su * (1.f - r1), w2 = su * r1;
  samples[(size_t)i * 3 + 0] = w0 * vb[i0 * 3 + 0] + w1 * vb[i1 * 3 + 0] + w2 * vb[i2 * 3 + 0];
  samples[(size_t)i * 3 + 1] = w0 * vb[i0 * 3 + 1] + w1 * vb[i1 * 3 + 1] + w2 * vb[i2 * 3 + 1];
  samples[(size_t)i * 3 + 2] = w0 * vb[i0 * 3 + 2] + w1 * vb[i1 * 3 + 2] + w2 * vb[i2 * 3 + 2];
}

__global__ void kChamfer(const float* X, const float* Y, unsigned* rowmin, int S) {
  int b = blockIdx.z;
  int i = blockIdx.x * TPB + threadIdx.x;
  int j0 = blockIdx.y * TPB;
  int n = min(TPB, S - j0);
  __shared__ float4 sy[TPB];
  const float* Yb = Y + ((size_t)b * S + j0) * 3;
  if ((int)threadIdx.x < n) {
    int t = threadIdx.x;
    sy[t] = make_float4(Yb[t * 3], Yb[t * 3 + 1], Yb[t * 3 + 2], 0.f);
  }
  __syncthreads();
  if (i >= S) return;
  const float* Xb = X + (size_t)b * S * 3;
  float x0 = Xb[i * 3], x1 = Xb[i * 3 + 1], x2 = Xb[i * 3 + 2];
  float inf = __int_as_float(0x7f800000);
  float m0 = inf, m1 = inf, m2 = inf, m3 = inf;
  int k = 0;
  for (; k + 4 <= n; k += 4) {
    float4 y0 = sy[k], y1 = sy[k + 1], y2 = sy[k + 2], y3 = sy[k + 3];
    float a0 = x0 - y0.x, b0 = x1 - y0.y, c0 = x2 - y0.z;
    float a1 = x0 - y1.x, b1 = x1 - y1.y, c1 = x2 - y1.z;
    float a2 = x0 - y2.x, b2 = x1 - y2.y, c2 = x2 - y2.z;
    float a3 = x0 - y3.x, b3 = x1 - y3.y, c3 = x2 - y3.z;
    m0 = fminf(m0, a0 * a0 + b0 * b0 + c0 * c0);
    m1 = fminf(m1, a1 * a1 + b1 * b1 + c1 * c1);
    m2 = fminf(m2, a2 * a2 + b2 * b2 + c2 * c2);
    m3 = fminf(m3, a3 * a3 + b3 * b3 + c3 * c3);
  }
  for (; k < n; k++) {
    float4 y = sy[k];
    float a = x0 - y.x, bb = x1 - y.y, cc = x2 - y.z;
    m0 = fminf(m0, a * a + bb * bb + cc * cc);
  }
  float mn = fminf(fminf(m0, m1), fminf(m2, m3));
  atomicMin(&rowmin[(size_t)b * S + i], __float_as_uint(mn));
}

__global__ void kReduceRowmin(const unsigned* rm, int n, double* acc) {
  int i = blockIdx.x * TPB + threadIdx.x;
  double v = 0.0;
  if (i < n) v = (double)__uint_as_float(rm[i]);
  double r = bredsum(v);
  if (threadIdx.x == 0) atomAddD(acc, r);
}

__global__ void kEdgeStd(const float* vstd, const int* edges, int E, double* acc) {
  int i = blockIdx.x * TPB + threadIdx.x;
  double val = 0.0;
  if (i < E) {
    int e0 = edges[(size_t)i * 2], e1 = edges[(size_t)i * 2 + 1];
    double dx = (double)vstd[e0 * 3 + 0] - vstd[e1 * 3 + 0];
    double dy = (double)vstd[e0 * 3 + 1] - vstd[e1 * 3 + 1];
    double dz = (double)vstd[e0 * 3 + 2] - vstd[e1 * 3 + 2];
    val = sqrt(dx * dx + dy * dy + dz * dz);
  }
  double r = bredsum(val);
  if (threadIdx.x == 0) atomAddD(acc, r);
}

__global__ void kEdgeLoss(const float* vscr, const int* edges, int B, int Vn, int E,
                          const double* tacc, double* acc) {
  int i = blockIdx.x * TPB + threadIdx.x;
  double tl = tacc[0] / (double)E;
  double val = 0.0;
  if (i < B * E) {
    int b = i / E, e = i % E;
    const float* vb = vscr + (size_t)b * Vn * 3;
    int e0 = edges[(size_t)e * 2], e1 = edges[(size_t)e * 2 + 1];
    double dx = (double)vb[e0 * 3 + 0] - vb[e1 * 3 + 0];
    double dy = (double)vb[e0 * 3 + 1] - vb[e1 * 3 + 1];
    double dz = (double)vb[e0 * 3 + 2] - vb[e1 * 3 + 2];
    double l = sqrt(dx * dx + dy * dy + dz * dz);
    double d = l - tl;
    val = d * d;
  }
  double r = bredsum(val);
  if (threadIdx.x == 0) atomAddD(acc, r);
}

__global__ void kAdjCount(const int* faces, int* deg, int F) {
  int f = blockIdx.x * TPB + threadIdx.x;
  if (f >= F) return;
  atomicAdd(&deg[faces[f * 3 + 0]], 1);
  atomicAdd(&deg[faces[f * 3 + 1]], 1);
  atomicAdd(&deg[faces[f * 3 + 2]], 1);
}

__global__ void kAdjScan(const int* deg, int* rowstart, int Vn) {
  __shared__ int s[1024];
  int t = threadIdx.x;
  int ch = (Vn + 1023) / 1024;
  int begin = t * ch;
  int end = begin + ch; if (end > Vn) end = Vn;
  int sum = 0;
  for (int i = begin; i < end; i++) sum += deg[i];
  s[t] = sum;
  __syncthreads();
  for (int o = 1; o < 1024; o <<= 1) {
    int ad = (t >= o) ? s[t - o] : 0;
    __syncthreads();
    s[t] += ad;
    __syncthreads();
  }
  int run = s[t] - sum;
  for (int i = begin; i < end; i++) { rowstart[i] = run; run += deg[i]; }
  if (t == 1023) rowstart[Vn] = s[1023];
}

__global__ void kAdjFill(const int* faces, const int* rowstart, int* pos, int* adj, int F) {
  int f = blockIdx.x * TPB + threadIdx.x;
  if (f >= F) return;
  for (int c = 0; c < 3; c++) {
    int v = faces[f * 3 + c];
    int slot = atomicAdd(&pos[v], 1);
    adj[rowstart[v] + slot] = (f << 2) | c;
  }
}

// ---- per-vertex: Laplacian norm + ARAP S accumulate + Kabsch R ----
__global__ void kVertexLapR(const float* vstd, const float* vscr, const int* faces,
                            const int* rowstart, const int* adj, const double* scot,
                            const double* ccot, double* Rmat, int B, int Vn, int F,
                            double* accLap) {
  int idx = blockIdx.x * TPB + threadIdx.x;
  double vlap = 0.0;
  if (idx < B * Vn) {
    int b = idx / Vn, v = idx % Vn;
    const float* cb = vscr + (size_t)b * Vn * 3;
    double pasx = vstd[v * 3], pasy = vstd[v * 3 + 1], pasz = vstd[v * 3 + 2];
    double pacx = cb[v * 3], pacy = cb[v * 3 + 1], pacz = cb[v * 3 + 2];
    int s0 = rowstart[v], s1 = rowstart[v + 1];
    double S00 = 0, S01 = 0, S02 = 0, S10 = 0, S11 = 0, S12 = 0, S20 = 0, S21 = 0, S22 = 0;
    double Lx = 0, Ly = 0, Lz = 0, rw = 0;
    for (int k = s0; k < s1; k++) {
      int code = adj[k];
      int f = code >> 2, c = code & 3;
      int j0 = faces[f * 3], j1 = faces[f * 3 + 1], j2 = faces[f * 3 + 2];
      int jb, jc, o1, o2;
      if (c == 0)      { jb = j1; jc = j2; o1 = 1; o2 = 2; }
      else if (c == 1) { jb = j2; jc = j0; o1 = 2; o2 = 0; }
      else             { jb = j0; jc = j1; o1 = 0; o2 = 1; }
      double cBs = scot[(size_t)f * 3 + o1], cCs = scot[(size_t)f * 3 + o2];
      size_t cbase = ((size_t)b * F + f) * 3;
      double cBc = ccot[cbase + o1], cCc = ccot[cbase + o2];
      double pbsx = vstd[jb * 3], pbsy = vstd[jb * 3 + 1], pbsz = vstd[jb * 3 + 2];
      double pcsx = vstd[jc * 3], pcsy = vstd[jc * 3 + 1], pcsz = vstd[jc * 3 + 2];
      double pbcx = cb[jb * 3], pbcy = cb[jb * 3 + 1], pbcz = cb[jb * 3 + 2];
      double pccx = cb[jc * 3], pccy = cb[jc * 3 + 1], pccz = cb[jc * 3 + 2];
      Lx += cCc * pbcx + cBc * pccx;
      Ly += cCc * pbcy + cBc * pccy;
      Lz += cCc * pbcz + cBc * pccz;
      rw += cBc + cCc;
      double e1sx = pasx - pbsx, e1sy = pasy - pbsy, e1sz = pasz - pbsz;
      double e2sx = pasx - pcsx, e2sy = pasy - pcsy, e2sz = pasz - pcsz;
      double e1cx = pacx - pbcx, e1cy = pacy - pbcy, e1cz = pacz - pbcz;
      double e2cx = pacx - pccx, e2cy = pacy - pccy, e2cz = pacz - pccz;
      S00 += cCs * e1sx * e1cx + cBs * e2sx * e2cx;
      S01 += cCs * e1sx * e1cy + cBs * e2sx * e2cy;
      S02 += cCs * e1sx * e1cz + cBs * e2sx * e2cz;
      S10 += cCs * e1sy * e1cx + cBs * e2sy * e2cx;
      S11 += cCs * e1sy * e1cy + cBs * e2sy * e2cy;
      S12 += cCs * e1sy * e1cz + cBs * e2sy * e2cz;
      S20 += cCs * e1sz * e1cx + cBs * e2sz * e2cx;
      S21 += cCs * e1sz * e1cy + cBs * e2sz * e2cy;
      S22 += cCs * e1sz * e1cz + cBs * e2sz * e2cz;
    }
    double inv = (rw > 0.0) ? 1.0 / fmax(rw, 1e-12) : 0.0;
    double dx = Lx * inv - pacx, dy = Ly * inv - pacy, dz = Lz * inv - pacz;
    vlap = sqrt(dx * dx + dy * dy + dz * dz);
    double S[3][3] = {{S00, S01, S02}, {S10, S11, S12}, {S20, S21, S22}};
    double R9[9];
    kabschR(S, R9);
    double* rp = Rmat + (size_t)idx * 9;
#pragma unroll
    for (int r = 0; r < 9; r++) rp[r] = R9[r];
  }
  double r1 = bredsum(vlap);
  if (threadIdx.x == 0) atomAddD(accLap, r1);
}

// ---- per-(b,face) rigid residual using precomputed R ----
__global__ void kRigidRes(const float* vstd, const float* vscr, const int* faces,
                          const double* scot, const double* Rmat, int B, int Vn, int F,
                          double* acc) {
  int i = blockIdx.x * TPB + threadIdx.x;
  double val = 0.0;
  if (i < B * F) {
    int b = i / F, f = i % F;
    int i0 = faces[f * 3], i1 = faces[f * 3 + 1], i2 = faces[f * 3 + 2];
    const float* cb = vscr + (size_t)b * Vn * 3;
    double cs0 = scot[(size_t)f * 3], cs1 = scot[(size_t)f * 3 + 1], cs2 = scot[(size_t)f * 3 + 2];
    double p0x = vstd[i0 * 3], p0y = vstd[i0 * 3 + 1], p0z = vstd[i0 * 3 + 2];
    double p1x = vstd[i1 * 3], p1y = vstd[i1 * 3 + 1], p1z = vstd[i1 * 3 + 2];
    double p2x = vstd[i2 * 3], p2y = vstd[i2 * 3 + 1], p2z = vstd[i2 * 3 + 2];
    double q0x = cb[i0 * 3], q0y = cb[i0 * 3 + 1], q0z = cb[i0 * 3 + 2];
    double q1x = cb[i1 * 3], q1y = cb[i1 * 3 + 1], q1z = cb[i1 * 3 + 2];
    double q2x = cb[i2 * 3], q2y = cb[i2 * 3 + 1], q2z = cb[i2 * 3 + 2];
    double e01s[3] = {p0x - p1x, p0y - p1y, p0z - p1z};
    double e02s[3] = {p0x - p2x, p0y - p2y, p0z - p2z};
    double e12s[3] = {p1x - p2x, p1y - p2y, p1z - p2z};
    double e01c[3] = {q0x - q1x, q0y - q1y, q0z - q1z};
    double e02c[3] = {q0x - q2x, q0y - q2y, q0z - q2z};
    double e12c[3] = {q1x - q2x, q1y - q2y, q1z - q2z};
    const double* R0 = Rmat + ((size_t)b * Vn + i0) * 9;
    const double* R1 = Rmat + ((size_t)b * Vn + i1) * 9;
    const double* R2 = Rmat + ((size_t)b * Vn + i2) * 9;
    val = cs1 * resid(R0, e02s, e02c) + cs2 * resid(R0, e01s, e01c)
        + cs0 * resid(R1, e12s, e12c) + cs2 * resid(R1, e01s, e01c)
        + cs1 * resid(R2, e02s, e02c) + cs0 * resid(R2, e12s, e12c);
  }
  double r = bredsum(val);
  if (threadIdx.x == 0) atomAddD(acc, r);
}

__global__ void kFinalize(const double* acc, float* out, int B, int Vn, int S, int E) {
  if (blockIdx.x == 0 && threadIdx.x == 0) {
    out[0] = (float)(acc[0] / ((double)B * S));
    out[1] = 1e-5f;
    out[2] = (float)(acc[1] / ((double)B * Vn));
    out[3] = (float)(acc[3] / ((double)B * E));
    out[4] = (float)(acc[4] / ((double)B * Vn));
  }
}

extern "C" void kernel_launch(void* const* d_in, const int* in_sizes, int n_in,
                              void* d_out, int out_size, void* d_ws, size_t ws_size,
                              hipStream_t stream) {
  const float* vscr = (const float*)d_in[0];
  const float* vstd = (const float*)d_in[1];
  const float* trg  = (const float*)d_in[2];
  const float* rfu  = (const float*)d_in[3];
  const float* rby  = (const float*)d_in[4];
  const int* faces  = (const int*)d_in[5];
  const int* edges  = (const int*)d_in[6];
  float* out = (float*)d_out;

  int nVs = in_sizes[1];
  int Vn = nVs / 3;
  int B = in_sizes[0] / nVs;
  int S = in_sizes[3] / B;
  int F = in_sizes[5] / 3;
  int E = in_sizes[6] / 2;
  int nc = (F + 1023) / 1024;

  char* p = (char*)d_ws;
  auto alloc = [&](size_t bytes) -> void* {
    void* r = (void*)p;
    p += (bytes + 255) & ~(size_t)255;
    return r;
  };
  double* cdf   = (double*)alloc((size_t)B * F * sizeof(double));
  double* bsum  = (double*)alloc((size_t)B * nc * sizeof(double));
  double* boffs = (double*)alloc((size_t)B * nc * sizeof(double));
  double* scot  = (double*)alloc((size_t)F * 3 * sizeof(double));
  double* ccot  = (double*)alloc((size_t)B * F * 3 * sizeof(double));
  double* Rmat  = (double*)alloc((size_t)B * Vn * 9 * sizeof(double));
  float* samples   = (float*)alloc((size_t)B * S * 3 * sizeof(float));
  unsigned* rowmin = (unsigned*)alloc((size_t)2 * B * S * sizeof(unsigned));
  int* degpos   = (int*)alloc((size_t)2 * Vn * sizeof(int));
  int* deg      = degpos;
  int* pos      = degpos + Vn;
  int* rowstart = (int*)alloc((size_t)(Vn + 1) * sizeof(int));
  int* adj      = (int*)alloc((size_t)3 * F * sizeof(int));
  double* accum = (double*)alloc(8 * sizeof(double));

  hipMemsetAsync(degpos, 0, (size_t)2 * Vn * sizeof(int), stream);
  hipMemsetAsync(accum, 0, 8 * sizeof(double), stream);

  int nrm = 2 * B * S;
  kInitRowmin<<<(nrm + TPB - 1) / TPB, TPB, 0, stream>>>(rowmin, nrm);

  kAdjCount<<<(F + TPB - 1) / TPB, TPB, 0, stream>>>(faces, deg, F);
  kAdjScan<<<1, 1024, 0, stream>>>(deg, rowstart, Vn);
  kAdjFill<<<(F + TPB - 1) / TPB, TPB, 0, stream>>>(faces, rowstart, pos, adj, F);

  kFacePrepScr<<<(B * F + TPB - 1) / TPB, TPB, 0, stream>>>(vscr, faces, cdf, ccot, B, Vn, F);
  kFacePrepStd<<<(F + TPB - 1) / TPB, TPB, 0, stream>>>(vstd, faces, scot, F);
  kScan1<<<B * nc, 1024, 0, stream>>>(cdf, bsum, F, nc);
  kScan2<<<B, 1024, 0, stream>>>(bsum, boffs, nc);
  kScan3<<<B * nc, 1024, 0, stream>>>(cdf, boffs, F, nc);
  kSample<<<(B * S + TPB - 1) / TPB, TPB, 0, stream>>>(vscr, faces, cdf, rfu, rby,
                                                       samples, B, Vn, F, S);
  dim3 cg((S + TPB - 1) / TPB, (S + TPB - 1) / TPB, B);
  kChamfer<<<cg, TPB, 0, stream>>>(samples, trg, rowmin, S);
  kChamfer<<<cg, TPB, 0, stream>>>(trg, samples, rowmin + (size_t)B * S, S);
  kReduceRowmin<<<(nrm + TPB - 1) / TPB, TPB, 0, stream>>>(rowmin, nrm, accum + 0);

  kEdgeStd<<<(E + TPB - 1) / TPB, TPB, 0, stream>>>(vstd, edges, E, accum + 2);
  kEdgeLoss<<<(B * E + TPB - 1) / TPB, TPB, 0, stream>>>(vscr, edges, B, Vn, E,
                                                         accum + 2, accum + 3);

  kVertexLapR<<<(B * Vn + TPB - 1) / TPB, TPB, 0, stream>>>(vstd, vscr, faces,
                                                            rowstart, adj, scot, ccot,
                                                            Rmat, B, Vn, F, accum + 1);
  kRigidRes<<<(B * F + TPB - 1) / TPB, TPB, 0, stream>>>(vstd, vscr, faces, scot,
                                                         Rmat, B, Vn, F, accum + 4);

  kFinalize<<<1, 1, 0, stream>>>(accum, out, B, Vn, S, E);
}

// Round 4
// 200.116 us; speedup vs baseline: 2.4066x; 1.3159x over previous
//
#include <hip/hip_runtime.h>
#include <math.h>

#define TPB 256
#define MAXDEG 8

static __device__ __forceinline__ void atomAddD(double* p, double v) {
  __hip_atomic_fetch_add(p, v, __ATOMIC_RELAXED, __HIP_MEMORY_SCOPE_AGENT);
}

static __device__ __forceinline__ double bredsum(double v) {
  __shared__ double sb[TPB];
  int t = threadIdx.x;
  sb[t] = v;
  __syncthreads();
  for (int o = TPB / 2; o > 0; o >>= 1) {
    if (t < o) sb[t] += sb[t + o];
    __syncthreads();
  }
  double r = sb[0];
  __syncthreads();
  return r;
}

// one Jacobi rotation, all indices compile-time -> stays in registers
template <int p, int q, int r>
static __device__ __forceinline__ void jrot(double A[3][3], double V[3][3]) {
  double apq = A[p][q];
  if (apq == 0.0) return;
  double app = A[p][p], aqq = A[q][q];
  double theta = (aqq - app) / (2.0 * apq);
  double t = 1.0 / (fabs(theta) + sqrt(theta * theta + 1.0));
  if (theta < 0.0) t = -t;
  double c = 1.0 / sqrt(t * t + 1.0), sn = t * c;
  A[p][p] = app - t * apq;
  A[q][q] = aqq + t * apq;
  A[p][q] = 0.0;
  A[q][p] = 0.0;
  double arp = A[r][p], arq = A[r][q];
  A[r][p] = c * arp - sn * arq; A[p][r] = A[r][p];
  A[r][q] = sn * arp + c * arq; A[q][r] = A[r][q];
#pragma unroll
  for (int k = 0; k < 3; k++) {
    double vkp = V[k][p], vkq = V[k][q];
    V[k][p] = c * vkp - sn * vkq;
    V[k][q] = sn * vkp + c * vkq;
  }
}

#define ESWAP(la, lax, lay, laz, lb, lbx, lby, lbz)                       \
  if (la < lb) {                                                          \
    double t_;                                                            \
    t_ = la; la = lb; lb = t_;                                            \
    t_ = lax; lax = lbx; lbx = t_;                                        \
    t_ = lay; lay = lby; lby = t_;                                        \
    t_ = laz; laz = lbz; lbz = t_;                                        \
  }

// Kabsch rotation via Jacobi eigen of S^T S; det-flip handled by
// R = v1 u1^T + v2 u2^T + (v1 x v2)(u1 x u2)^T   (all static indexing)
static __device__ void kabschR(const double S[3][3], double R9[9]) {
  double A[3][3];
#pragma unroll
  for (int a = 0; a < 3; a++)
#pragma unroll
    for (int c = 0; c < 3; c++)
      A[a][c] = S[0][a] * S[0][c] + S[1][a] * S[1][c] + S[2][a] * S[2][c];
  double V[3][3] = {{1, 0, 0}, {0, 1, 0}, {0, 0, 1}};
  for (int sw = 0; sw < 12; sw++) {
    double off = fabs(A[0][1]) + fabs(A[0][2]) + fabs(A[1][2]);
    double dia = fabs(A[0][0]) + fabs(A[1][1]) + fabs(A[2][2]);
    if (!(off > dia * 1e-15)) break;
    jrot<0, 1, 2>(A, V);
    jrot<0, 2, 1>(A, V);
    jrot<1, 2, 0>(A, V);
  }
  double l0 = A[0][0], l1 = A[1][1], l2 = A[2][2];
  double a0x = V[0][0], a0y = V[1][0], a0z = V[2][0];
  double a1x = V[0][1], a1y = V[1][1], a1z = V[2][1];
  double a2x = V[0][2], a2y = V[1][2], a2z = V[2][2];
  ESWAP(l0, a0x, a0y, a0z, l1, a1x, a1y, a1z);
  ESWAP(l0, a0x, a0y, a0z, l2, a2x, a2y, a2z);
  ESWAP(l1, a1x, a1y, a1z, l2, a2x, a2y, a2z);
  double R00 = 1, R01 = 0, R02 = 0, R10 = 0, R11 = 1, R12 = 0, R20 = 0, R21 = 0, R22 = 1;
  double b1x = S[0][0] * a0x + S[0][1] * a0y + S[0][2] * a0z;
  double b1y = S[1][0] * a0x + S[1][1] * a0y + S[1][2] * a0z;
  double b1z = S[2][0] * a0x + S[2][1] * a0y + S[2][2] * a0z;
  double b2x = S[0][0] * a1x + S[0][1] * a1y + S[0][2] * a1z;
  double b2y = S[1][0] * a1x + S[1][1] * a1y + S[1][2] * a1z;
  double b2z = S[2][0] * a1x + S[2][1] * a1y + S[2][2] * a1z;
  double n1 = sqrt(b1x * b1x + b1y * b1y + b1z * b1z);
  if (n1 > 1e-300 && isfinite(n1)) {
    double u1x = b1x / n1, u1y = b1y / n1, u1z = b1z / n1;
    double dp = u1x * b2x + u1y * b2y + u1z * b2z;
    b2x -= dp * u1x; b2y -= dp * u1y; b2z -= dp * u1z;
    double n2 = sqrt(b2x * b2x + b2y * b2y + b2z * b2z);
    double u2x, u2y, u2z;
    if (n2 > n1 * 1e-14) {
      u2x = b2x / n2; u2y = b2y / n2; u2z = b2z / n2;
    } else {
      double f0 = fabs(u1x), f1 = fabs(u1y), f2 = fabs(u1z);
      double e0, e1, e2;
      if (f0 <= f1 && f0 <= f2) { e0 = 1.0 - u1x * u1x; e1 = -u1x * u1y; e2 = -u1x * u1z; }
      else if (f1 <= f2)        { e0 = -u1y * u1x; e1 = 1.0 - u1y * u1y; e2 = -u1y * u1z; }
      else                      { e0 = -u1z * u1x; e1 = -u1z * u1y; e2 = 1.0 - u1z * u1z; }
      double nw = sqrt(e0 * e0 + e1 * e1 + e2 * e2);
      u2x = e0 / nw; u2y = e1 / nw; u2z = e2 / nw;
    }
    double u3x = u1y * u2z - u1z * u2y;
    double u3y = u1z * u2x - u1x * u2z;
    double u3z = u1x * u2y - u1y * u2x;
    double w3x = a0y * a1z - a0z * a1y;
    double w3y = a0z * a1x - a0x * a1z;
    double w3z = a0x * a1y - a0y * a1x;
    R00 = a0x * u1x + a1x * u2x + w3x * u3x;
    R01 = a0x * u1y + a1x * u2y + w3x * u3y;
    R02 = a0x * u1z + a1x * u2z + w3x * u3z;
    R10 = a0y * u1x + a1y * u2x + w3y * u3x;
    R11 = a0y * u1y + a1y * u2y + w3y * u3y;
    R12 = a0y * u1z + a1y * u2z + w3y * u3z;
    R20 = a0z * u1x + a1z * u2x + w3z * u3x;
    R21 = a0z * u1y + a1z * u2y + w3z * u3y;
    R22 = a0z * u1z + a1z * u2z + w3z * u3z;
  }
  R9[0] = R00; R9[1] = R01; R9[2] = R02;
  R9[3] = R10; R9[4] = R11; R9[5] = R12;
  R9[6] = R20; R9[7] = R21; R9[8] = R22;
}

static __device__ __forceinline__ double resid(const double* R, const double* es,
                                               const double* ec) {
  double r0 = ec[0] - (R[0] * es[0] + R[1] * es[1] + R[2] * es[2]);
  double r1 = ec[1] - (R[3] * es[0] + R[4] * es[1] + R[5] * es[2]);
  double r2 = ec[2] - (R[6] * es[0] + R[7] * es[1] + R[8] * es[2]);
  return r0 * r0 + r1 * r1 + r2 * r2;
}

__global__ void kInitRowmin(unsigned* rm, int n) {
  int i = blockIdx.x * blockDim.x + threadIdx.x;
  if (i < n) rm[i] = 0x7f800000u;  // +inf
}

// per-(b,f): sampling area + scr cots; b==0 threads also write std cots
__global__ void kFacePrep(const float* verts, const float* vstd, const int* faces,
                          double* areas, double* ccot, double* scot,
                          int B, int Vn, int F) {
  int i = blockIdx.x * blockDim.x + threadIdx.x;
  if (i >= B * F) return;
  int b = i / F, f = i % F;
  const float* vb = verts + (size_t)b * Vn * 3;
  int i0 = faces[f * 3], i1 = faces[f * 3 + 1], i2 = faces[f * 3 + 2];
  {
    double p0x = vb[i0 * 3], p0y = vb[i0 * 3 + 1], p0z = vb[i0 * 3 + 2];
    double p1x = vb[i1 * 3], p1y = vb[i1 * 3 + 1], p1z = vb[i1 * 3 + 2];
    double p2x = vb[i2 * 3], p2y = vb[i2 * 3 + 1], p2z = vb[i2 * 3 + 2];
    double ax = p1x - p0x, ay = p1y - p0y, az = p1z - p0z;
    double bx = p2x - p0x, by = p2y - p0y, bz = p2z - p0z;
    double cx = ay * bz - az * by, cy = az * bx - ax * bz, cz = ax * by - ay * bx;
    areas[i] = 0.5 * sqrt(cx * cx + cy * cy + cz * cz);
    double dx = p1x - p2x, dy = p1y - p2y, dz = p1z - p2z;
    double A2 = dx * dx + dy * dy + dz * dz;
    double B2 = bx * bx + by * by + bz * bz;
    double C2 = ax * ax + ay * ay + az * az;
    double A = sqrt(A2), Bl = sqrt(B2), C = sqrt(C2);
    double s = 0.5 * (A + Bl + C);
    double pr = s * (s - A) * (s - Bl) * (s - C);
    pr = pr < 1e-12 ? 1e-12 : pr;
    double inv4 = 1.0 / (4.0 * sqrt(pr));
    ccot[(size_t)i * 3 + 0] = (B2 + C2 - A2) * inv4;
    ccot[(size_t)i * 3 + 1] = (A2 + C2 - B2) * inv4;
    ccot[(size_t)i * 3 + 2] = (A2 + B2 - C2) * inv4;
  }
  if (b == 0) {
    double p0x = vstd[i0 * 3], p0y = vstd[i0 * 3 + 1], p0z = vstd[i0 * 3 + 2];
    double p1x = vstd[i1 * 3], p1y = vstd[i1 * 3 + 1], p1z = vstd[i1 * 3 + 2];
    double p2x = vstd[i2 * 3], p2y = vstd[i2 * 3 + 1], p2z = vstd[i2 * 3 + 2];
    double ax = p1x - p0x, ay = p1y - p0y, az = p1z - p0z;
    double bx = p2x - p0x, by = p2y - p0y, bz = p2z - p0z;
    double dx = p1x - p2x, dy = p1y - p2y, dz = p1z - p2z;
    double A2 = dx * dx + dy * dy + dz * dz;
    double B2 = bx * bx + by * by + bz * bz;
    double C2 = ax * ax + ay * ay + az * az;
    double A = sqrt(A2), Bl = sqrt(B2), C = sqrt(C2);
    double s = 0.5 * (A + Bl + C);
    double pr = s * (s - A) * (s - Bl) * (s - C);
    pr = pr < 1e-12 ? 1e-12 : pr;
    double inv4 = 1.0 / (4.0 * sqrt(pr));
    scot[(size_t)f * 3 + 0] = (B2 + C2 - A2) * inv4;
    scot[(size_t)f * 3 + 1] = (A2 + C2 - B2) * inv4;
    scot[(size_t)f * 3 + 2] = (A2 + B2 - C2) * inv4;
  }
}

// two-level inclusive scan over F doubles per batch (chunk = 1024)
__global__ void kScan1(double* a, double* bsum, int F, int nc) {
  int blk = blockIdx.x;
  int b = blk / nc, c = blk % nc;
  int t = threadIdx.x;
  int f = c * 1024 + t;
  __shared__ double s[1024];
  double v = (f < F) ? a[(size_t)b * F + f] : 0.0;
  s[t] = v;
  __syncthreads();
  for (int o = 1; o < 1024; o <<= 1) {
    double ad = (t >= o) ? s[t - o] : 0.0;
    __syncthreads();
    s[t] += ad;
    __syncthreads();
  }
  if (f < F) a[(size_t)b * F + f] = s[t];
  if (t == 1023) bsum[(size_t)b * nc + c] = s[1023];
}

__global__ void kScan2(const double* bsum, double* boffs, int nc) {
  int b = blockIdx.x, t = threadIdx.x;
  __shared__ double s[1024];
  double v = (t < nc) ? bsum[(size_t)b * nc + t] : 0.0;
  s[t] = v;
  __syncthreads();
  for (int o = 1; o < 1024; o <<= 1) {
    double ad = (t >= o) ? s[t - o] : 0.0;
    __syncthreads();
    s[t] += ad;
    __syncthreads();
  }
  if (t < nc) boffs[(size_t)b * nc + t] = s[t] - v;  // exclusive
}

__global__ void kScan3(double* a, const double* boffs, int F, int nc) {
  int blk = blockIdx.x;
  int b = blk / nc, c = blk % nc;
  int f = c * 1024 + threadIdx.x;
  if (f < F) a[(size_t)b * F + f] += boffs[(size_t)b * nc + c];
}

__global__ void kSample(const float* verts, const int* faces, const double* cdf,
                        const float* rfu, const float* rbary, float* samples,
                        int B, int Vn, int F, int S) {
  int i = blockIdx.x * blockDim.x + threadIdx.x;
  if (i >= B * S) return;
  int b = i / S;
  const double* c = cdf + (size_t)b * F;
  double total = c[F - 1];
  double tgt = (double)rfu[i] * total;
  int lo = 0, hi = F;
  while (lo < hi) {
    int m = (lo + hi) >> 1;
    if (c[m] < tgt) lo = m + 1; else hi = m;
  }
  int f = lo < F ? lo : F - 1;
  const float* vb = verts + (size_t)b * Vn * 3;
  int i0 = faces[f * 3], i1 = faces[f * 3 + 1], i2 = faces[f * 3 + 2];
  float r0 = rbary[(size_t)i * 2], r1 = rbary[(size_t)i * 2 + 1];
  float su = sqrtf(r0);
  float w0 = 1.f - su, w1 = su * (1.f - r1), w2 = su * r1;
  samples[(size_t)i * 3 + 0] = w0 * vb[i0 * 3 + 0] + w1 * vb[i1 * 3 + 0] + w2 * vb[i2 * 3 + 0];
  samples[(size_t)i * 3 + 1] = w0 * vb[i0 * 3 + 1] + w1 * vb[i1 * 3 + 1] + w2 * vb[i2 * 3 + 1];
  samples[(size_t)i * 3 + 2] = w0 * vb[i0 * 3 + 2] + w1 * vb[i1 * 3 + 2] + w2 * vb[i2 * 3 + 2];
}

__global__ void kChamfer(const float* X, const float* Y, unsigned* rowmin, int S) {
  int b = blockIdx.z;
  int i = blockIdx.x * TPB + threadIdx.x;
  int j0 = blockIdx.y * TPB;
  int n = min(TPB, S - j0);
  __shared__ float4 sy[TPB];
  const float* Yb = Y + ((size_t)b * S + j0) * 3;
  if ((int)threadIdx.x < n) {
    int t = threadIdx.x;
    sy[t] = make_float4(Yb[t * 3], Yb[t * 3 + 1], Yb[t * 3 + 2], 0.f);
  }
  __syncthreads();
  if (i >= S) return;
  const float* Xb = X + (size_t)b * S * 3;
  float x0 = Xb[i * 3], x1 = Xb[i * 3 + 1], x2 = Xb[i * 3 + 2];
  float inf = __int_as_float(0x7f800000);
  float m0 = inf, m1 = inf, m2 = inf, m3 = inf;
  int k = 0;
  for (; k + 4 <= n; k += 4) {
    float4 y0 = sy[k], y1 = sy[k + 1], y2 = sy[k + 2], y3 = sy[k + 3];
    float a0 = x0 - y0.x, b0 = x1 - y0.y, c0 = x2 - y0.z;
    float a1 = x0 - y1.x, b1 = x1 - y1.y, c1 = x2 - y1.z;
    float a2 = x0 - y2.x, b2 = x1 - y2.y, c2 = x2 - y2.z;
    float a3 = x0 - y3.x, b3 = x1 - y3.y, c3 = x2 - y3.z;
    m0 = fminf(m0, a0 * a0 + b0 * b0 + c0 * c0);
    m1 = fminf(m1, a1 * a1 + b1 * b1 + c1 * c1);
    m2 = fminf(m2, a2 * a2 + b2 * b2 + c2 * c2);
    m3 = fminf(m3, a3 * a3 + b3 * b3 + c3 * c3);
  }
  for (; k < n; k++) {
    float4 y = sy[k];
    float a = x0 - y.x, bb = x1 - y.y, cc = x2 - y.z;
    m0 = fminf(m0, a * a + bb * bb + cc * cc);
  }
  float mn = fminf(fminf(m0, m1), fminf(m2, m3));
  atomicMin(&rowmin[(size_t)b * S + i], __float_as_uint(mn));
}

__global__ void kReduceRowmin(const unsigned* rm, int n, double* acc) {
  int i = blockIdx.x * TPB + threadIdx.x;
  double v = 0.0;
  if (i < n) v = (double)__uint_as_float(rm[i]);
  double r = bredsum(v);
  if (threadIdx.x == 0) atomAddD(acc, r);
}

__global__ void kEdgeStd(const float* vstd, const int* edges, int E, double* acc) {
  int i = blockIdx.x * TPB + threadIdx.x;
  double val = 0.0;
  if (i < E) {
    int e0 = edges[(size_t)i * 2], e1 = edges[(size_t)i * 2 + 1];
    double dx = (double)vstd[e0 * 3 + 0] - vstd[e1 * 3 + 0];
    double dy = (double)vstd[e0 * 3 + 1] - vstd[e1 * 3 + 1];
    double dz = (double)vstd[e0 * 3 + 2] - vstd[e1 * 3 + 2];
    val = sqrt(dx * dx + dy * dy + dz * dz);
  }
  double r = bredsum(val);
  if (threadIdx.x == 0) atomAddD(acc, r);
}

__global__ void kEdgeLoss(const float* vscr, const int* edges, int B, int Vn, int E,
                          const double* tacc, double* acc) {
  int i = blockIdx.x * TPB + threadIdx.x;
  double tl = tacc[0] / (double)E;
  double val = 0.0;
  if (i < B * E) {
    int b = i / E, e = i % E;
    const float* vb = vscr + (size_t)b * Vn * 3;
    int e0 = edges[(size_t)e * 2], e1 = edges[(size_t)e * 2 + 1];
    double dx = (double)vb[e0 * 3 + 0] - vb[e1 * 3 + 0];
    double dy = (double)vb[e0 * 3 + 1] - vb[e1 * 3 + 1];
    double dz = (double)vb[e0 * 3 + 2] - vb[e1 * 3 + 2];
    double l = sqrt(dx * dx + dy * dy + dz * dz);
    double d = l - tl;
    val = d * d;
  }
  double r = bredsum(val);
  if (threadIdx.x == 0) atomAddD(acc, r);
}

// ---- fixed-cap adjacency: adjtab[v][slot] = {jb, jc, f*3+o1, f*3+o2} ----
__global__ void kAdjFill(const int* faces, int* cnt, int4* adjtab, int F) {
  int f = blockIdx.x * TPB + threadIdx.x;
  if (f >= F) return;
  int j0 = faces[f * 3], j1 = faces[f * 3 + 1], j2 = faces[f * 3 + 2];
  int f3 = f * 3;
  int s0 = atomicAdd(&cnt[j0], 1);
  if (s0 < MAXDEG) adjtab[(size_t)j0 * MAXDEG + s0] = make_int4(j1, j2, f3 + 1, f3 + 2);
  int s1 = atomicAdd(&cnt[j1], 1);
  if (s1 < MAXDEG) adjtab[(size_t)j1 * MAXDEG + s1] = make_int4(j2, j0, f3 + 2, f3 + 0);
  int s2 = atomicAdd(&cnt[j2], 1);
  if (s2 < MAXDEG) adjtab[(size_t)j2 * MAXDEG + s2] = make_int4(j0, j1, f3 + 0, f3 + 1);
}

// ---- per-vertex: Laplacian norm + ARAP S accumulate + Kabsch R ----
__global__ void kVertexLapR(const float* vstd, const float* vscr,
                            const int* cnt, const int4* adjtab, const double* scot,
                            const double* ccot, double* Rmat, int B, int Vn, int F,
                            double* accLap) {
  int idx = blockIdx.x * TPB + threadIdx.x;
  double vlap = 0.0;
  if (idx < B * Vn) {
    int b = idx / Vn, v = idx % Vn;
    const float* cb = vscr + (size_t)b * Vn * 3;
    const double* ccb = ccot + (size_t)b * F * 3;
    double pasx = vstd[v * 3], pasy = vstd[v * 3 + 1], pasz = vstd[v * 3 + 2];
    double pacx = cb[v * 3], pacy = cb[v * 3 + 1], pacz = cb[v * 3 + 2];
    int n = cnt[v];
    if (n > MAXDEG) n = MAXDEG;
    const int4* at = adjtab + (size_t)v * MAXDEG;
    double S00 = 0, S01 = 0, S02 = 0, S10 = 0, S11 = 0, S12 = 0, S20 = 0, S21 = 0, S22 = 0;
    double Lx = 0, Ly = 0, Lz = 0, rw = 0;
    for (int k = 0; k < n; k++) {
      int4 e = at[k];
      int jb = e.x, jc = e.y;
      double cBs = scot[e.z], cCs = scot[e.w];
      double cBc = ccb[e.z], cCc = ccb[e.w];
      double pbsx = vstd[jb * 3], pbsy = vstd[jb * 3 + 1], pbsz = vstd[jb * 3 + 2];
      double pcsx = vstd[jc * 3], pcsy = vstd[jc * 3 + 1], pcsz = vstd[jc * 3 + 2];
      double pbcx = cb[jb * 3], pbcy = cb[jb * 3 + 1], pbcz = cb[jb * 3 + 2];
      double pccx = cb[jc * 3], pccy = cb[jc * 3 + 1], pccz = cb[jc * 3 + 2];
      Lx += cCc * pbcx + cBc * pccx;
      Ly += cCc * pbcy + cBc * pccy;
      Lz += cCc * pbcz + cBc * pccz;
      rw += cBc + cCc;
      double e1sx = pasx - pbsx, e1sy = pasy - pbsy, e1sz = pasz - pbsz;
      double e2sx = pasx - pcsx, e2sy = pasy - pcsy, e2sz = pasz - pcsz;
      double e1cx = pacx - pbcx, e1cy = pacy - pbcy, e1cz = pacz - pbcz;
      double e2cx = pacx - pccx, e2cy = pacy - pccy, e2cz = pacz - pccz;
      S00 += cCs * e1sx * e1cx + cBs * e2sx * e2cx;
      S01 += cCs * e1sx * e1cy + cBs * e2sx * e2cy;
      S02 += cCs * e1sx * e1cz + cBs * e2sx * e2cz;
      S10 += cCs * e1sy * e1cx + cBs * e2sy * e2cx;
      S11 += cCs * e1sy * e1cy + cBs * e2sy * e2cy;
      S12 += cCs * e1sy * e1cz + cBs * e2sy * e2cz;
      S20 += cCs * e1sz * e1cx + cBs * e2sz * e2cx;
      S21 += cCs * e1sz * e1cy + cBs * e2sz * e2cy;
      S22 += cCs * e1sz * e1cz + cBs * e2sz * e2cz;
    }
    double inv = (rw > 0.0) ? 1.0 / fmax(rw, 1e-12) : 0.0;
    double dx = Lx * inv - pacx, dy = Ly * inv - pacy, dz = Lz * inv - pacz;
    vlap = sqrt(dx * dx + dy * dy + dz * dz);
    double S[3][3] = {{S00, S01, S02}, {S10, S11, S12}, {S20, S21, S22}};
    double R9[9];
    kabschR(S, R9);
    double* rp = Rmat + (size_t)idx * 9;
#pragma unroll
    for (int r = 0; r < 9; r++) rp[r] = R9[r];
  }
  double r1 = bredsum(vlap);
  if (threadIdx.x == 0) atomAddD(accLap, r1);
}

// ---- per-(b,face) rigid residual using precomputed R ----
__global__ void kRigidRes(const float* vstd, const float* vscr, const int* faces,
                          const double* scot, const double* Rmat, int B, int Vn, int F,
                          double* acc) {
  int i = blockIdx.x * TPB + threadIdx.x;
  double val = 0.0;
  if (i < B * F) {
    int b = i / F, f = i % F;
    int i0 = faces[f * 3], i1 = faces[f * 3 + 1], i2 = faces[f * 3 + 2];
    const float* cb = vscr + (size_t)b * Vn * 3;
    double cs0 = scot[(size_t)f * 3], cs1 = scot[(size_t)f * 3 + 1], cs2 = scot[(size_t)f * 3 + 2];
    double p0x = vstd[i0 * 3], p0y = vstd[i0 * 3 + 1], p0z = vstd[i0 * 3 + 2];
    double p1x = vstd[i1 * 3], p1y = vstd[i1 * 3 + 1], p1z = vstd[i1 * 3 + 2];
    double p2x = vstd[i2 * 3], p2y = vstd[i2 * 3 + 1], p2z = vstd[i2 * 3 + 2];
    double q0x = cb[i0 * 3], q0y = cb[i0 * 3 + 1], q0z = cb[i0 * 3 + 2];
    double q1x = cb[i1 * 3], q1y = cb[i1 * 3 + 1], q1z = cb[i1 * 3 + 2];
    double q2x = cb[i2 * 3], q2y = cb[i2 * 3 + 1], q2z = cb[i2 * 3 + 2];
    double e01s[3] = {p0x - p1x, p0y - p1y, p0z - p1z};
    double e02s[3] = {p0x - p2x, p0y - p2y, p0z - p2z};
    double e12s[3] = {p1x - p2x, p1y - p2y, p1z - p2z};
    double e01c[3] = {q0x - q1x, q0y - q1y, q0z - q1z};
    double e02c[3] = {q0x - q2x, q0y - q2y, q0z - q2z};
    double e12c[3] = {q1x - q2x, q1y - q2y, q1z - q2z};
    const double* R0 = Rmat + ((size_t)b * Vn + i0) * 9;
    const double* R1 = Rmat + ((size_t)b * Vn + i1) * 9;
    const double* R2 = Rmat + ((size_t)b * Vn + i2) * 9;
    val = cs1 * resid(R0, e02s, e02c) + cs2 * resid(R0, e01s, e01c)
        + cs0 * resid(R1, e12s, e12c) + cs2 * resid(R1, e01s, e01c)
        + cs1 * resid(R2, e02s, e02c) + cs0 * resid(R2, e12s, e12c);
  }
  double r = bredsum(val);
  if (threadIdx.x == 0) atomAddD(acc, r);
}

__global__ void kFinalize(const double* acc, float* out, int B, int Vn, int S, int E) {
  if (blockIdx.x == 0 && threadIdx.x == 0) {
    out[0] = (float)(acc[0] / ((double)B * S));
    out[1] = 1e-5f;
    out[2] = (float)(acc[1] / ((double)B * Vn));
    out[3] = (float)(acc[3] / ((double)B * E));
    out[4] = (float)(acc[4] / ((double)B * Vn));
  }
}

extern "C" void kernel_launch(void* const* d_in, const int* in_sizes, int n_in,
                              void* d_out, int out_size, void* d_ws, size_t ws_size,
                              hipStream_t stream) {
  const float* vscr = (const float*)d_in[0];
  const float* vstd = (const float*)d_in[1];
  const float* trg  = (const float*)d_in[2];
  const float* rfu  = (const float*)d_in[3];
  const float* rby  = (const float*)d_in[4];
  const int* faces  = (const int*)d_in[5];
  const int* edges  = (const int*)d_in[6];
  float* out = (float*)d_out;

  int nVs = in_sizes[1];
  int Vn = nVs / 3;
  int B = in_sizes[0] / nVs;
  int S = in_sizes[3] / B;
  int F = in_sizes[5] / 3;
  int E = in_sizes[6] / 2;
  int nc = (F + 1023) / 1024;

  char* p = (char*)d_ws;
  auto alloc = [&](size_t bytes) -> void* {
    void* r = (void*)p;
    p += (bytes + 255) & ~(size_t)255;
    return r;
  };
  double* cdf   = (double*)alloc((size_t)B * F * sizeof(double));
  double* bsum  = (double*)alloc((size_t)B * nc * sizeof(double));
  double* boffs = (double*)alloc((size_t)B * nc * sizeof(double));
  double* scot  = (double*)alloc((size_t)F * 3 * sizeof(double));
  double* ccot  = (double*)alloc((size_t)B * F * 3 * sizeof(double));
  double* Rmat  = (double*)alloc((size_t)B * Vn * 9 * sizeof(double));
  float* samples   = (float*)alloc((size_t)B * S * 3 * sizeof(float));
  unsigned* rowmin = (unsigned*)alloc((size_t)2 * B * S * sizeof(unsigned));
  int* adjcnt   = (int*)alloc((size_t)Vn * sizeof(int));
  int4* adjtab  = (int4*)alloc((size_t)Vn * MAXDEG * sizeof(int4));
  double* accum = (double*)alloc(8 * sizeof(double));

  hipMemsetAsync(adjcnt, 0, (size_t)Vn * sizeof(int), stream);
  hipMemsetAsync(accum, 0, 8 * sizeof(double), stream);

  int nrm = 2 * B * S;
  kInitRowmin<<<(nrm + TPB - 1) / TPB, TPB, 0, stream>>>(rowmin, nrm);

  kAdjFill<<<(F + TPB - 1) / TPB, TPB, 0, stream>>>(faces, adjcnt, adjtab, F);

  kFacePrep<<<(B * F + TPB - 1) / TPB, TPB, 0, stream>>>(vscr, vstd, faces, cdf, ccot,
                                                         scot, B, Vn, F);
  kScan1<<<B * nc, 1024, 0, stream>>>(cdf, bsum, F, nc);
  kScan2<<<B, 1024, 0, stream>>>(bsum, boffs, nc);
  kScan3<<<B * nc, 1024, 0, stream>>>(cdf, boffs, F, nc);
  kSample<<<(B * S + TPB - 1) / TPB, TPB, 0, stream>>>(vscr, faces, cdf, rfu, rby,
                                                       samples, B, Vn, F, S);
  dim3 cg((S + TPB - 1) / TPB, (S + TPB - 1) / TPB, B);
  kChamfer<<<cg, TPB, 0, stream>>>(samples, trg, rowmin, S);
  kChamfer<<<cg, TPB, 0, stream>>>(trg, samples, rowmin + (size_t)B * S, S);
  kReduceRowmin<<<(nrm + TPB - 1) / TPB, TPB, 0, stream>>>(rowmin, nrm, accum + 0);

  kEdgeStd<<<(E + TPB - 1) / TPB, TPB, 0, stream>>>(vstd, edges, E, accum + 2);
  kEdgeLoss<<<(B * E + TPB - 1) / TPB, TPB, 0, stream>>>(vscr, edges, B, Vn, E,
                                                         accum + 2, accum + 3);

  kVertexLapR<<<(B * Vn + TPB - 1) / TPB, TPB, 0, stream>>>(vstd, vscr, adjcnt, adjtab,
                                                            scot, ccot, Rmat, B, Vn, F,
                                                            accum + 1);
  kRigidRes<<<(B * F + TPB - 1) / TPB, TPB, 0, stream>>>(vstd, vscr, faces, scot,
                                                         Rmat, B, Vn, F, accum + 4);

  kFinalize<<<1, 1, 0, stream>>>(accum, out, B, Vn, S, E);
}